// Round 3
// baseline (722.002 us; speedup 1.0000x reference)
//
#include <hip/hip_runtime.h>
#include <math.h>

// Problem constants: N=20000, E=320000, C=64, NS=4, NB=8, NH=64
#define PI_F        3.14159265358979323846f
#define SQRT2_F     1.41421356237309515f
#define SQRT3_F     1.73205080756887729f
#define INV_SQRT3_F 0.57735026918962576f
#define INV_AVG     0.25f   // 1/sqrt(16)

#define N_NODES 20000
#define N_EDGES 320000

typedef float v2f __attribute__((ext_vector_type(2)));
typedef float v4f __attribute__((ext_vector_type(4)));

__device__ __forceinline__ float swish_f(float x) {
    return x / (1.f + __expf(-x));
}

// ---------------------------------------------------------------------------
// Edge counting sort by receiver. Launch-bounds experiment (round 3): the
// measured occupancy tracks the 2nd __launch_bounds__ arg (r0/r2: (256,4)->40%
// regardless of VGPR=64/LDS; r1: (256,8)->82%), i.e. the compiler granulates
// the register file to the requested waves/EU. Small kernels get (256,8)
// (live regs << 64-reg budget); k_edge gets (256,6) (85-reg budget > 64 used,
// vs (256,8)'s 64-reg budget which spilled catastrophically in r1).
// ---------------------------------------------------------------------------
__global__ __launch_bounds__(256, 8) void k_zero_cnt(int* __restrict__ cnt) {
    const int i = blockIdx.x * 256 + threadIdx.x;
    if (i < N_NODES) cnt[i] = 0;
}
__global__ __launch_bounds__(256, 8) void k_hist(const int* __restrict__ rcv,
                                                 int* __restrict__ cnt) {
    const int e = blockIdx.x * 256 + threadIdx.x;
    if (e < N_EDGES) atomicAdd(&cnt[rcv[e]], 1);
}
__global__ __launch_bounds__(1024) void k_scan(const int* __restrict__ cnt,
                                               int* __restrict__ cursor) {
    __shared__ int part[1024];
    const int t = threadIdx.x;
    const int base = t * 20;
    int s = 0;
    #pragma unroll
    for (int j = 0; j < 20; ++j) {
        const int idx = base + j;
        if (idx < N_NODES) s += cnt[idx];
    }
    part[t] = s;
    __syncthreads();
    for (int d = 1; d < 1024; d <<= 1) {
        const int v = (t >= d) ? part[t - d] : 0;
        __syncthreads();
        part[t] += v;
        __syncthreads();
    }
    int run = (t == 0) ? 0 : part[t - 1];
    for (int j = 0; j < 20; ++j) {
        const int idx = base + j;
        if (idx < N_NODES) { cursor[idx] = run; run += cnt[idx]; }
    }
}
__global__ __launch_bounds__(256, 8) void k_scatter(const int* __restrict__ rcv,
                                                    int* __restrict__ cursor,
                                                    int* __restrict__ perm) {
    const int e = blockIdx.x * 256 + threadIdx.x;
    if (e < N_EDGES) {
        const int pos = atomicAdd(&cursor[rcv[e]], 1);
        perm[pos] = e;
    }
}

// ---------------------------------------------------------------------------
// K1: node up-projection + agg zero-init. (256,8): ~20 live VGPRs, safe.
// ---------------------------------------------------------------------------
__global__ __launch_bounds__(256, 8) void k_node_up(
    const float* __restrict__ ns, const float* __restrict__ nv,
    const float* __restrict__ Wus, const float* __restrict__ Wuv,
    float* __restrict__ s_up, float* __restrict__ v_up,
    float* __restrict__ agg_s, float* __restrict__ agg_v)
{
    const int lane = threadIdx.x & 63;
    const int wq   = __builtin_amdgcn_readfirstlane(threadIdx.x >> 6);
    const int n    = blockIdx.x * 4 + wq;

    const float* nsr = ns + n * 64;
    const float* nvr = nv + n * 192;
    float acc = 0.f, a0 = 0.f, a1 = 0.f, a2 = 0.f;
    for (int i = 0; i < 64; ++i) {
        const float s = nsr[i];
        acc = fmaf(s, Wus[i*64 + lane], acc);
        const float wv = Wuv[i*64 + lane];
        a0 = fmaf(nvr[i*3+0], wv, a0);
        a1 = fmaf(nvr[i*3+1], wv, a1);
        a2 = fmaf(nvr[i*3+2], wv, a2);
    }
    s_up[n*64 + lane] = acc;
    v_up[(n*64 + lane)*3 + 0] = a0;
    v_up[(n*64 + lane)*3 + 1] = a1;
    v_up[(n*64 + lane)*3 + 2] = a2;

    agg_s[n*128 + lane]      = 0.f;
    agg_s[n*128 + 64 + lane] = 0.f;
    #pragma unroll
    for (int k = 0; k < 6; ++k) agg_v[n*384 + k*64 + lane] = 0.f;
}

// ---------------------------------------------------------------------------
// K2 v9 (OCCUPANCY, SAFE BUDGET): byte-identical to v8 except
// __launch_bounds__(256, 6) -> 85-reg budget (current use: 64), target
// 6 waves/EU resident instead of 4. v8 evidence: VALUBusy 64%, Occ 40%,
// zero bank conflicts, no spill -> the remaining 36% issue-idle is
// gather/atomic/DS latency that 4 waves/SIMD cannot hide.
// ---------------------------------------------------------------------------
__global__ __launch_bounds__(256, 6) void k_edge(
    const float* __restrict__ vecs,
    const int*   __restrict__ snd_idx, const int* __restrict__ rcv_idx,
    const int*   __restrict__ perm,
    const float* __restrict__ W0, const float* __restrict__ W1,
    const float* __restrict__ W2,
    const float* __restrict__ s_up, const float* __restrict__ v_up,
    float* __restrict__ agg_s, float* __restrict__ agg_v)
{
    __shared__ float hv[64*68];   // [ch][le], stride 68; holds h1 then h2

    const int tid  = threadIdx.x;
    const int lane = tid & 63;
    const int wq   = __builtin_amdgcn_readfirstlane(tid >> 6);
    const int e0   = blockIdx.x * 64;
    const int c    = lane & 15, q = lane >> 4;

    // --- per-lane metadata for sorted slot e0+lane (all 64 edges) ---
    const int pe_l  = perm[e0 + lane];
    const int rcv_l = rcv_idx[pe_l];
    const int snd_l = snd_idx[pe_l];
    const float vx_l = vecs[pe_l*3+0], vy_l = vecs[pe_l*3+1], vz_l = vecs[pe_l*3+2];
    const float x_l  = sqrtf(vx_l*vx_l + vy_l*vy_l + vz_l*vz_l);
    const float sx_l = (x_l == 0.f) ? 1.f : x_l;
    const float ys_l = SQRT3_F / sx_l;
    const float Y0_l = vx_l * ys_l, Y1_l = vy_l * ys_l, Y2_l = vz_l * ys_l;
    const float msk_l = (x_l == 0.f) ? 0.f : 1.f;

    // ---- A1: bessel + layer0 -> h1, channel=lane, edges le=wq*16+t ----
    float h1o[16];
    #pragma unroll 4
    for (int t = 0; t < 16; ++t) {
        const int le = wq*16 + t;
        const float x = __shfl(x_l, le);
        const float sx = (x == 0.f) ? 1.f : x;
        float s1, c1;
        __sincosf(PI_F * x, &s1, &c1);
        const float u  = fminf(x, 1.f);
        const float u2 = u*u, u3 = u2*u;
        const float u6 = u3*u3, u7 = u6*u, u8 = u6*u2;
        const float env  = (x < 1.f) ? (1.f - 28.f*u6 + 48.f*u7 - 21.f*u8) : 0.f;
        const float pref = SQRT2_F * env / sx;
        float h1 = 0.f;
        float sn = s1, snm1 = 0.f;
        const float twoc = 2.f * c1;
        #pragma unroll
        for (int b = 0; b < 8; ++b) {
            h1 = fmaf(pref * sn, W0[b*64 + lane], h1);
            const float snext = fmaf(twoc, sn, -snm1);
            snm1 = sn; sn = snext;
        }
        h1o[t] = swish_f(h1);
    }
    {   // write own channel-row, own wave's 16 edge-columns: 4x ds_write_b128
        float* dst = hv + lane*68 + wq*16;
        #pragma unroll
        for (int k = 0; k < 4; ++k)
            ((v4f*)dst)[k] = (v4f){h1o[4*k], h1o[4*k+1], h1o[4*k+2], h1o[4*k+3]};
    }
    // no barrier: A2 reads only columns wq*16..+15, written by this wave.

    // ---- A2: h2 = swish(h1 @ W1); reads all rows i fully, then overwrites
    //      own row (=lane) of the same columns. lane = output channel.
    {
        v2f acc2[8];
        #pragma unroll
        for (int tp = 0; tp < 8; ++tp) acc2[tp] = (v2f){0.f, 0.f};
        const float* hbase = hv + wq*16;
        for (int i = 0; i < 64; ++i) {
            const float w = W1[i*64 + lane];           // coalesced, L1-hot
            const v2f wv = {w, w};
            const v4f* hp4 = (const v4f*)(hbase + i*68);
            #pragma unroll
            for (int k = 0; k < 4; ++k) {
                const v4f h4 = hp4[k];
                const v2f hlo = __builtin_shufflevector(h4, h4, 0, 1);
                const v2f hhi = __builtin_shufflevector(h4, h4, 2, 3);
                acc2[2*k]   = __builtin_elementwise_fma(hlo, wv, acc2[2*k]);
                acc2[2*k+1] = __builtin_elementwise_fma(hhi, wv, acc2[2*k+1]);
            }
        }
        float* dst = hv + lane*68 + wq*16;
        #pragma unroll
        for (int k = 0; k < 4; ++k)
            ((v4f*)dst)[k] = (v4f){swish_f(acc2[2*k][0]),   swish_f(acc2[2*k][1]),
                                   swish_f(acc2[2*k+1][0]), swish_f(acc2[2*k+1][1])};
    }
    __syncthreads();

    // ---- B: mixp[t/2][ntl] pairs; lane (c,q) of wave wq accumulates
    //      mix[64wq + ntl*16 + c][le = q*16 + t] for t=0..15.
    v2f mixp[8][4];
    #pragma unroll
    for (int tp = 0; tp < 8; ++tp)
        #pragma unroll
        for (int j = 0; j < 4; ++j) mixp[tp][j] = (v2f){0.f, 0.f};
    {
        const float* W2c = W2 + 64*wq + c;
        const float* hq  = hv + q*16;
        for (int i = 0; i < 64; ++i) {
            const float w0 = W2c[i*256 +  0];
            const float w1 = W2c[i*256 + 16];
            const float w2 = W2c[i*256 + 32];
            const float w3 = W2c[i*256 + 48];
            const v2f w0v = {w0,w0}, w1v = {w1,w1}, w2v = {w2,w2}, w3v = {w3,w3};
            const v4f* hp4 = (const v4f*)(hq + i*68);
            #pragma unroll
            for (int k = 0; k < 4; ++k) {
                const v4f h4 = hp4[k];
                const v2f hlo = __builtin_shufflevector(h4, h4, 0, 1);
                const v2f hhi = __builtin_shufflevector(h4, h4, 2, 3);
                mixp[2*k][0]   = __builtin_elementwise_fma(hlo, w0v, mixp[2*k][0]);
                mixp[2*k][1]   = __builtin_elementwise_fma(hlo, w1v, mixp[2*k][1]);
                mixp[2*k][2]   = __builtin_elementwise_fma(hlo, w2v, mixp[2*k][2]);
                mixp[2*k][3]   = __builtin_elementwise_fma(hlo, w3v, mixp[2*k][3]);
                mixp[2*k+1][0] = __builtin_elementwise_fma(hhi, w0v, mixp[2*k+1][0]);
                mixp[2*k+1][1] = __builtin_elementwise_fma(hhi, w1v, mixp[2*k+1][1]);
                mixp[2*k+1][2] = __builtin_elementwise_fma(hhi, w2v, mixp[2*k+1][2]);
                mixp[2*k+1][3] = __builtin_elementwise_fma(hhi, w3v, mixp[2*k+1][3]);
            }
        }
    }
    #define MIXR(t,j) (mixp[(t)>>1][j][(t)&1])

    // ---- C: per-q-group segmented scatter-add from registers (v5) ----
    int cur = -1;
    if (wq == 0) {            // agg_s[:, ntl*16+c] += msv * mix0
        float ra0=0.f, ra1=0.f, ra2=0.f, ra3=0.f;
        #pragma unroll
        for (int t = 0; t < 16; ++t) {
            const int sl  = (lane & 48) + t;
            const int rcv = __shfl(rcv_l, sl);
            const int snd = __shfl(snd_l, sl);
            const float msk = __shfl(msk_l, sl);
            if (rcv != cur) {
                if (cur >= 0) {
                    float* p = agg_s + cur*128 + c;
                    unsafeAtomicAdd(p,      ra0);
                    unsafeAtomicAdd(p + 16, ra1);
                    unsafeAtomicAdd(p + 32, ra2);
                    unsafeAtomicAdd(p + 48, ra3);
                }
                ra0 = ra1 = ra2 = ra3 = 0.f; cur = rcv;
            }
            const float* sp = s_up + snd*64 + c;
            ra0 = fmaf(sp[0],  MIXR(t,0) * msk, ra0);
            ra1 = fmaf(sp[16], MIXR(t,1) * msk, ra1);
            ra2 = fmaf(sp[32], MIXR(t,2) * msk, ra2);
            ra3 = fmaf(sp[48], MIXR(t,3) * msk, ra3);
        }
        float* p = agg_s + cur*128 + c;
        unsafeAtomicAdd(p,      ra0);
        unsafeAtomicAdd(p + 16, ra1);
        unsafeAtomicAdd(p + 32, ra2);
        unsafeAtomicAdd(p + 48, ra3);
    } else if (wq == 1) {     // agg_s[:, 64+ntl*16+c] += (mv.Y)/sqrt3 * mix1
        float ra0=0.f, ra1=0.f, ra2=0.f, ra3=0.f;
        #pragma unroll
        for (int t = 0; t < 16; ++t) {
            const int sl  = (lane & 48) + t;
            const int rcv = __shfl(rcv_l, sl);
            const int snd = __shfl(snd_l, sl);
            const float msk = __shfl(msk_l, sl);
            const float Y0 = __shfl(Y0_l, sl), Y1 = __shfl(Y1_l, sl), Y2 = __shfl(Y2_l, sl);
            if (rcv != cur) {
                if (cur >= 0) {
                    float* p = agg_s + cur*128 + 64 + c;
                    unsafeAtomicAdd(p,      ra0);
                    unsafeAtomicAdd(p + 16, ra1);
                    unsafeAtomicAdd(p + 32, ra2);
                    unsafeAtomicAdd(p + 48, ra3);
                }
                ra0 = ra1 = ra2 = ra3 = 0.f; cur = rcv;
            }
            const float* vp = v_up + (snd*64 + c)*3;
            const float t00 = (vp[  0]*Y0 + vp[  1]*Y1 + vp[  2]*Y2) * INV_SQRT3_F;
            const float t01 = (vp[ 48]*Y0 + vp[ 49]*Y1 + vp[ 50]*Y2) * INV_SQRT3_F;
            const float t02 = (vp[ 96]*Y0 + vp[ 97]*Y1 + vp[ 98]*Y2) * INV_SQRT3_F;
            const float t03 = (vp[144]*Y0 + vp[145]*Y1 + vp[146]*Y2) * INV_SQRT3_F;
            ra0 = fmaf(t00, MIXR(t,0) * msk, ra0);
            ra1 = fmaf(t01, MIXR(t,1) * msk, ra1);
            ra2 = fmaf(t02, MIXR(t,2) * msk, ra2);
            ra3 = fmaf(t03, MIXR(t,3) * msk, ra3);
        }
        float* p = agg_s + cur*128 + 64 + c;
        unsafeAtomicAdd(p,      ra0);
        unsafeAtomicAdd(p + 16, ra1);
        unsafeAtomicAdd(p + 32, ra2);
        unsafeAtomicAdd(p + 48, ra3);
    } else if (wq == 2) {     // agg_v[:, ntl*16+c, m] += mv_m * mix2
        float rv[4][3];
        #pragma unroll
        for (int i = 0; i < 4; ++i) { rv[i][0]=0.f; rv[i][1]=0.f; rv[i][2]=0.f; }
        #pragma unroll
        for (int t = 0; t < 16; ++t) {
            const int sl  = (lane & 48) + t;
            const int rcv = __shfl(rcv_l, sl);
            const int snd = __shfl(snd_l, sl);
            const float msk = __shfl(msk_l, sl);
            if (rcv != cur) {
                if (cur >= 0) {
                    float* p = agg_v + cur*384 + c*3;
                    #pragma unroll
                    for (int ntl = 0; ntl < 4; ++ntl)
                        #pragma unroll
                        for (int m = 0; m < 3; ++m)
                            unsafeAtomicAdd(p + ntl*48 + m, rv[ntl][m]);
                }
                #pragma unroll
                for (int i = 0; i < 4; ++i) { rv[i][0]=0.f; rv[i][1]=0.f; rv[i][2]=0.f; }
                cur = rcv;
            }
            const float* vp = v_up + (snd*64 + c)*3;
            #pragma unroll
            for (int ntl = 0; ntl < 4; ++ntl) {
                const float mx = MIXR(t,ntl) * msk;
                #pragma unroll
                for (int m = 0; m < 3; ++m)
                    rv[ntl][m] = fmaf(vp[ntl*48 + m], mx, rv[ntl][m]);
            }
        }
        float* p = agg_v + cur*384 + c*3;
        #pragma unroll
        for (int ntl = 0; ntl < 4; ++ntl)
            #pragma unroll
            for (int m = 0; m < 3; ++m)
                unsafeAtomicAdd(p + ntl*48 + m, rv[ntl][m]);
    } else {                  // agg_v[:, 64+ntl*16+c, m] += msv * Y_m * mix3
        float rv[4][3];
        #pragma unroll
        for (int i = 0; i < 4; ++i) { rv[i][0]=0.f; rv[i][1]=0.f; rv[i][2]=0.f; }
        #pragma unroll
        for (int t = 0; t < 16; ++t) {
            const int sl  = (lane & 48) + t;
            const int rcv = __shfl(rcv_l, sl);
            const int snd = __shfl(snd_l, sl);
            const float msk = __shfl(msk_l, sl);
            const float Y0 = __shfl(Y0_l, sl), Y1 = __shfl(Y1_l, sl), Y2 = __shfl(Y2_l, sl);
            if (rcv != cur) {
                if (cur >= 0) {
                    float* p = agg_v + cur*384 + 192 + c*3;
                    #pragma unroll
                    for (int ntl = 0; ntl < 4; ++ntl)
                        #pragma unroll
                        for (int m = 0; m < 3; ++m)
                            unsafeAtomicAdd(p + ntl*48 + m, rv[ntl][m]);
                }
                #pragma unroll
                for (int i = 0; i < 4; ++i) { rv[i][0]=0.f; rv[i][1]=0.f; rv[i][2]=0.f; }
                cur = rcv;
            }
            const float* sp = s_up + snd*64 + c;
            #pragma unroll
            for (int ntl = 0; ntl < 4; ++ntl) {
                const float mm = sp[ntl*16] * (MIXR(t,ntl) * msk);
                rv[ntl][0] = fmaf(mm, Y0, rv[ntl][0]);
                rv[ntl][1] = fmaf(mm, Y1, rv[ntl][1]);
                rv[ntl][2] = fmaf(mm, Y2, rv[ntl][2]);
            }
        }
        float* p = agg_v + cur*384 + 192 + c*3;
        #pragma unroll
        for (int ntl = 0; ntl < 4; ++ntl)
            #pragma unroll
            for (int m = 0; m < 3; ++m)
                unsafeAtomicAdd(p + ntl*48 + m, rv[ntl][m]);
    }
    #undef MIXR
}

// ---------------------------------------------------------------------------
// K3: node down-projection + specie skip + swish gating. (256,8): ~25 live
// VGPRs, safe under the 64-reg budget.
// ---------------------------------------------------------------------------
__global__ __launch_bounds__(256, 8) void k_node_down(
    const float* __restrict__ ns, const float* __restrict__ nv,
    const int*   __restrict__ spec_idx,
    const float* __restrict__ Wds, const float* __restrict__ Wdv,
    const float* __restrict__ Wsks, const float* __restrict__ Wskv,
    const float* __restrict__ agg_s, const float* __restrict__ agg_v,
    float* __restrict__ out)
{
    const int lane = threadIdx.x & 63;
    const int wq   = __builtin_amdgcn_readfirstlane(threadIdx.x >> 6);
    const int n    = blockIdx.x * 4 + wq;
    const int spec = __builtin_amdgcn_readfirstlane(spec_idx[n]);

    const float* ar  = agg_s + n*128;
    const float* avr = agg_v + n*384;
    float s0 = 0.f, s1 = 0.f, v0 = 0.f, v1 = 0.f, v2 = 0.f;
    for (int i = 0; i < 128; ++i) {
        const float a = ar[i] * INV_AVG;
        s0 = fmaf(a, Wds[i*128 + lane], s0);
        s1 = fmaf(a, Wds[i*128 + 64 + lane], s1);
        const float wv = Wdv[i*64 + lane];
        v0 = fmaf(avr[i*3+0] * INV_AVG, wv, v0);
        v1 = fmaf(avr[i*3+1] * INV_AVG, wv, v1);
        v2 = fmaf(avr[i*3+2] * INV_AVG, wv, v2);
    }
    const float* nsr = ns + n*64;
    const float* nvr = nv + n*192;
    const float* Ws  = Wsks + spec*8192;   // (64,128)
    const float* Wv  = Wskv + spec*4096;   // (64,64)
    for (int i = 0; i < 64; ++i) {
        const float s = nsr[i];
        s0 = fmaf(s, Ws[i*128 + lane], s0);
        s1 = fmaf(s, Ws[i*128 + 64 + lane], s1);
        const float wv = Wv[i*64 + lane];
        v0 = fmaf(nvr[i*3+0], wv, v0);
        v1 = fmaf(nvr[i*3+1], wv, v1);
        v2 = fmaf(nvr[i*3+2], wv, v2);
    }
    const float scal = swish_f(s0);
    const float gate = swish_f(s1);
    out[n*256 + lane]               = scal;
    out[n*256 + 64 + lane*3 + 0]    = v0 * gate;
    out[n*256 + 64 + lane*3 + 1]    = v1 * gate;
    out[n*256 + 64 + lane*3 + 2]    = v2 * gate;
}

// ---------------------------------------------------------------------------
extern "C" void kernel_launch(void* const* d_in, const int* in_sizes, int n_in,
                              void* d_out, int out_size, void* d_ws, size_t ws_size,
                              hipStream_t stream)
{
    (void)in_sizes; (void)n_in; (void)out_size; (void)ws_size;

    const float* vectors      = (const float*)d_in[0];
    const float* node_scalars = (const float*)d_in[1];
    const float* node_vectors = (const float*)d_in[2];
    const int*   node_specie  = (const int*)d_in[3];
    const int*   senders      = (const int*)d_in[4];
    const int*   receivers    = (const int*)d_in[5];
    const float* W_skip_s     = (const float*)d_in[6];
    const float* W_skip_v     = (const float*)d_in[7];
    const float* W_up_s       = (const float*)d_in[8];
    const float* W_up_v       = (const float*)d_in[9];
    const float* W_mlp0       = (const float*)d_in[10];
    const float* W_mlp1       = (const float*)d_in[11];
    const float* W_mlp2       = (const float*)d_in[12];
    const float* W_down_s     = (const float*)d_in[13];
    const float* W_down_v     = (const float*)d_in[14];
    float* out = (float*)d_out;

    // workspace layout (round-2): 15,360,000 f32 + perm 320k ints.
    float* ws    = (float*)d_ws;
    float* s_up  = ws;                        // N*64   = 1,280,000 f32
    float* v_up  = s_up + 1280000;            // N*192  = 3,840,000
    float* agg_s = v_up + 3840000;            // N*128  = 2,560,000
    float* agg_v = agg_s + 2560000;           // N*384  = 7,680,000
    int*   perm  = (int*)(agg_v + 7680000);   // E ints = 320,000
    int*   cnt    = (int*)agg_s;              // aliased scratch (dead before node_up)
    int*   cursor = cnt + 20000;

    // edge counting sort by receiver
    hipLaunchKernelGGL(k_zero_cnt, dim3(79),   dim3(256),  0, stream, cnt);
    hipLaunchKernelGGL(k_hist,     dim3(1250), dim3(256),  0, stream, receivers, cnt);
    hipLaunchKernelGGL(k_scan,     dim3(1),    dim3(1024), 0, stream, cnt, cursor);
    hipLaunchKernelGGL(k_scatter,  dim3(1250), dim3(256),  0, stream, receivers, cursor, perm);

    hipLaunchKernelGGL(k_node_up, dim3(5000), dim3(256), 0, stream,
        node_scalars, node_vectors, W_up_s, W_up_v, s_up, v_up, agg_s, agg_v);
    hipLaunchKernelGGL(k_edge, dim3(5000), dim3(256), 0, stream,
        vectors, senders, receivers, perm, W_mlp0, W_mlp1, W_mlp2,
        s_up, v_up, agg_s, agg_v);
    hipLaunchKernelGGL(k_node_down, dim3(5000), dim3(256), 0, stream,
        node_scalars, node_vectors, node_specie, W_down_s, W_down_v,
        W_skip_s, W_skip_v, agg_s, agg_v, out);
}

// Round 4
// 633.368 us; speedup vs baseline: 1.1399x; 1.1399x over previous
//
#include <hip/hip_runtime.h>
#include <math.h>

// Problem constants: N=20000, E=320000, C=64, NS=4, NB=8, NH=64
#define PI_F        3.14159265358979323846f
#define SQRT2_F     1.41421356237309515f
#define SQRT3_F     1.73205080756887729f
#define INV_SQRT3_F 0.57735026918962576f
#define INV_AVG     0.25f   // 1/sqrt(16)

#define N_NODES 20000
#define N_EDGES 320000

typedef float v2f __attribute__((ext_vector_type(2)));
typedef float v4f __attribute__((ext_vector_type(4)));

__device__ __forceinline__ float swish_f(float x) {
    return x / (1.f + __expf(-x));
}

// ---------------------------------------------------------------------------
// LAUNCH-BOUNDS LAW (measured r0-r3): hipcc allocates VGPR budget = 256/min_waves
// exactly (w=4 -> 64, w=6 -> 40, w=8 -> 32) and spills whatever doesn't fit.
// k_edge live state ~90-100 regs -> only w=4 works (r1: w=8 -> 5.9GB scratch,
// 1845us; r3: w=6 -> 480MB scratch, 494us). k_edge stays (256,4) permanently.
// ---------------------------------------------------------------------------
__global__ __launch_bounds__(256, 8) void k_zero_cnt(int* __restrict__ cnt) {
    const int i = blockIdx.x * 256 + threadIdx.x;
    if (i < N_NODES) cnt[i] = 0;
}
__global__ __launch_bounds__(256, 8) void k_hist(const int* __restrict__ rcv,
                                                 int* __restrict__ cnt) {
    const int e = blockIdx.x * 256 + threadIdx.x;
    if (e < N_EDGES) atomicAdd(&cnt[rcv[e]], 1);
}
__global__ __launch_bounds__(1024) void k_scan(const int* __restrict__ cnt,
                                               int* __restrict__ cursor) {
    __shared__ int part[1024];
    const int t = threadIdx.x;
    const int base = t * 20;
    int s = 0;
    #pragma unroll
    for (int j = 0; j < 20; ++j) {
        const int idx = base + j;
        if (idx < N_NODES) s += cnt[idx];
    }
    part[t] = s;
    __syncthreads();
    for (int d = 1; d < 1024; d <<= 1) {
        const int v = (t >= d) ? part[t - d] : 0;
        __syncthreads();
        part[t] += v;
        __syncthreads();
    }
    int run = (t == 0) ? 0 : part[t - 1];
    for (int j = 0; j < 20; ++j) {
        const int idx = base + j;
        if (idx < N_NODES) { cursor[idx] = run; run += cnt[idx]; }
    }
}
__global__ __launch_bounds__(256, 8) void k_scatter(const int* __restrict__ rcv,
                                                    int* __restrict__ cursor,
                                                    int* __restrict__ perm) {
    const int e = blockIdx.x * 256 + threadIdx.x;
    if (e < N_EDGES) {
        const int pos = atomicAdd(&cursor[rcv[e]], 1);
        perm[pos] = e;
    }
}

// ---------------------------------------------------------------------------
// K1 v2 (WEIGHT-AMORTIZED): 4 nodes per wave. Each weight element Wus/Wuv
// [i*64+lane] is loaded ONCE and applied to 4 nodes -> L2 weight traffic
// 20000x32KB = 0.64GB -> 0.16GB. Node activations arrive via uniform s_loads
// (n0 wave-uniform). ~25 live VGPRs; plain bounds (no forced budget).
// Grid: 1250 blocks x 16 nodes.
// ---------------------------------------------------------------------------
__global__ __launch_bounds__(256) void k_node_up(
    const float* __restrict__ ns, const float* __restrict__ nv,
    const float* __restrict__ Wus, const float* __restrict__ Wuv,
    float* __restrict__ s_up, float* __restrict__ v_up,
    float* __restrict__ agg_s, float* __restrict__ agg_v)
{
    const int lane = threadIdx.x & 63;
    const int wq   = __builtin_amdgcn_readfirstlane(threadIdx.x >> 6);
    const int n0   = blockIdx.x * 16 + wq * 4;   // nodes n0..n0+3

    const float* ns0 = ns + n0 * 64;
    const float* nv0 = nv + n0 * 192;

    float acc[4] = {0.f, 0.f, 0.f, 0.f};
    float a[4][3] = {};
    for (int i = 0; i < 64; ++i) {
        const float ws = Wus[i*64 + lane];
        const float wv = Wuv[i*64 + lane];
        #pragma unroll
        for (int j = 0; j < 4; ++j) {
            const float s = ns0[j*64 + i];          // uniform -> s_load
            acc[j] = fmaf(s, ws, acc[j]);
            const float* nvr = nv0 + j*192 + i*3;   // uniform -> s_load
            a[j][0] = fmaf(nvr[0], wv, a[j][0]);
            a[j][1] = fmaf(nvr[1], wv, a[j][1]);
            a[j][2] = fmaf(nvr[2], wv, a[j][2]);
        }
    }
    #pragma unroll
    for (int j = 0; j < 4; ++j) {
        const int n = n0 + j;
        s_up[n*64 + lane] = acc[j];
        v_up[(n*64 + lane)*3 + 0] = a[j][0];
        v_up[(n*64 + lane)*3 + 1] = a[j][1];
        v_up[(n*64 + lane)*3 + 2] = a[j][2];
        agg_s[n*128 + lane]      = 0.f;
        agg_s[n*128 + 64 + lane] = 0.f;
        #pragma unroll
        for (int k = 0; k < 6; ++k) agg_v[n*384 + k*64 + lane] = 0.f;
    }
}

// ---------------------------------------------------------------------------
// K2 v8 (RESTORED): byte-identical to the round-2 measured-best k_edge
// (267us, VALUBusy 64%, no spill). See LAUNCH-BOUNDS LAW above for why
// (256,4) is final.
// ---------------------------------------------------------------------------
__global__ __launch_bounds__(256, 4) void k_edge(
    const float* __restrict__ vecs,
    const int*   __restrict__ snd_idx, const int* __restrict__ rcv_idx,
    const int*   __restrict__ perm,
    const float* __restrict__ W0, const float* __restrict__ W1,
    const float* __restrict__ W2,
    const float* __restrict__ s_up, const float* __restrict__ v_up,
    float* __restrict__ agg_s, float* __restrict__ agg_v)
{
    __shared__ float hv[64*68];   // [ch][le], stride 68; holds h1 then h2

    const int tid  = threadIdx.x;
    const int lane = tid & 63;
    const int wq   = __builtin_amdgcn_readfirstlane(tid >> 6);
    const int e0   = blockIdx.x * 64;
    const int c    = lane & 15, q = lane >> 4;

    // --- per-lane metadata for sorted slot e0+lane (all 64 edges) ---
    const int pe_l  = perm[e0 + lane];
    const int rcv_l = rcv_idx[pe_l];
    const int snd_l = snd_idx[pe_l];
    const float vx_l = vecs[pe_l*3+0], vy_l = vecs[pe_l*3+1], vz_l = vecs[pe_l*3+2];
    const float x_l  = sqrtf(vx_l*vx_l + vy_l*vy_l + vz_l*vz_l);
    const float sx_l = (x_l == 0.f) ? 1.f : x_l;
    const float ys_l = SQRT3_F / sx_l;
    const float Y0_l = vx_l * ys_l, Y1_l = vy_l * ys_l, Y2_l = vz_l * ys_l;
    const float msk_l = (x_l == 0.f) ? 0.f : 1.f;

    // ---- A1: bessel + layer0 -> h1, channel=lane, edges le=wq*16+t ----
    float h1o[16];
    #pragma unroll 4
    for (int t = 0; t < 16; ++t) {
        const int le = wq*16 + t;
        const float x = __shfl(x_l, le);
        const float sx = (x == 0.f) ? 1.f : x;
        float s1, c1;
        __sincosf(PI_F * x, &s1, &c1);
        const float u  = fminf(x, 1.f);
        const float u2 = u*u, u3 = u2*u;
        const float u6 = u3*u3, u7 = u6*u, u8 = u6*u2;
        const float env  = (x < 1.f) ? (1.f - 28.f*u6 + 48.f*u7 - 21.f*u8) : 0.f;
        const float pref = SQRT2_F * env / sx;
        float h1 = 0.f;
        float sn = s1, snm1 = 0.f;
        const float twoc = 2.f * c1;
        #pragma unroll
        for (int b = 0; b < 8; ++b) {
            h1 = fmaf(pref * sn, W0[b*64 + lane], h1);
            const float snext = fmaf(twoc, sn, -snm1);
            snm1 = sn; sn = snext;
        }
        h1o[t] = swish_f(h1);
    }
    {   // write own channel-row, own wave's 16 edge-columns: 4x ds_write_b128
        float* dst = hv + lane*68 + wq*16;
        #pragma unroll
        for (int k = 0; k < 4; ++k)
            ((v4f*)dst)[k] = (v4f){h1o[4*k], h1o[4*k+1], h1o[4*k+2], h1o[4*k+3]};
    }
    // no barrier: A2 reads only columns wq*16..+15, written by this wave.

    // ---- A2: h2 = swish(h1 @ W1); reads all rows i fully, then overwrites
    //      own row (=lane) of the same columns. lane = output channel.
    {
        v2f acc2[8];
        #pragma unroll
        for (int tp = 0; tp < 8; ++tp) acc2[tp] = (v2f){0.f, 0.f};
        const float* hbase = hv + wq*16;
        for (int i = 0; i < 64; ++i) {
            const float w = W1[i*64 + lane];           // coalesced, L1-hot
            const v2f wv = {w, w};
            const v4f* hp4 = (const v4f*)(hbase + i*68);
            #pragma unroll
            for (int k = 0; k < 4; ++k) {
                const v4f h4 = hp4[k];
                const v2f hlo = __builtin_shufflevector(h4, h4, 0, 1);
                const v2f hhi = __builtin_shufflevector(h4, h4, 2, 3);
                acc2[2*k]   = __builtin_elementwise_fma(hlo, wv, acc2[2*k]);
                acc2[2*k+1] = __builtin_elementwise_fma(hhi, wv, acc2[2*k+1]);
            }
        }
        float* dst = hv + lane*68 + wq*16;
        #pragma unroll
        for (int k = 0; k < 4; ++k)
            ((v4f*)dst)[k] = (v4f){swish_f(acc2[2*k][0]),   swish_f(acc2[2*k][1]),
                                   swish_f(acc2[2*k+1][0]), swish_f(acc2[2*k+1][1])};
    }
    __syncthreads();

    // ---- B: mixp[t/2][ntl] pairs; lane (c,q) of wave wq accumulates
    //      mix[64wq + ntl*16 + c][le = q*16 + t] for t=0..15.
    v2f mixp[8][4];
    #pragma unroll
    for (int tp = 0; tp < 8; ++tp)
        #pragma unroll
        for (int j = 0; j < 4; ++j) mixp[tp][j] = (v2f){0.f, 0.f};
    {
        const float* W2c = W2 + 64*wq + c;
        const float* hq  = hv + q*16;
        for (int i = 0; i < 64; ++i) {
            const float w0 = W2c[i*256 +  0];
            const float w1 = W2c[i*256 + 16];
            const float w2 = W2c[i*256 + 32];
            const float w3 = W2c[i*256 + 48];
            const v2f w0v = {w0,w0}, w1v = {w1,w1}, w2v = {w2,w2}, w3v = {w3,w3};
            const v4f* hp4 = (const v4f*)(hq + i*68);
            #pragma unroll
            for (int k = 0; k < 4; ++k) {
                const v4f h4 = hp4[k];
                const v2f hlo = __builtin_shufflevector(h4, h4, 0, 1);
                const v2f hhi = __builtin_shufflevector(h4, h4, 2, 3);
                mixp[2*k][0]   = __builtin_elementwise_fma(hlo, w0v, mixp[2*k][0]);
                mixp[2*k][1]   = __builtin_elementwise_fma(hlo, w1v, mixp[2*k][1]);
                mixp[2*k][2]   = __builtin_elementwise_fma(hlo, w2v, mixp[2*k][2]);
                mixp[2*k][3]   = __builtin_elementwise_fma(hlo, w3v, mixp[2*k][3]);
                mixp[2*k+1][0] = __builtin_elementwise_fma(hhi, w0v, mixp[2*k+1][0]);
                mixp[2*k+1][1] = __builtin_elementwise_fma(hhi, w1v, mixp[2*k+1][1]);
                mixp[2*k+1][2] = __builtin_elementwise_fma(hhi, w2v, mixp[2*k+1][2]);
                mixp[2*k+1][3] = __builtin_elementwise_fma(hhi, w3v, mixp[2*k+1][3]);
            }
        }
    }
    #define MIXR(t,j) (mixp[(t)>>1][j][(t)&1])

    // ---- C: per-q-group segmented scatter-add from registers (v5) ----
    int cur = -1;
    if (wq == 0) {            // agg_s[:, ntl*16+c] += msv * mix0
        float ra0=0.f, ra1=0.f, ra2=0.f, ra3=0.f;
        #pragma unroll
        for (int t = 0; t < 16; ++t) {
            const int sl  = (lane & 48) + t;
            const int rcv = __shfl(rcv_l, sl);
            const int snd = __shfl(snd_l, sl);
            const float msk = __shfl(msk_l, sl);
            if (rcv != cur) {
                if (cur >= 0) {
                    float* p = agg_s + cur*128 + c;
                    unsafeAtomicAdd(p,      ra0);
                    unsafeAtomicAdd(p + 16, ra1);
                    unsafeAtomicAdd(p + 32, ra2);
                    unsafeAtomicAdd(p + 48, ra3);
                }
                ra0 = ra1 = ra2 = ra3 = 0.f; cur = rcv;
            }
            const float* sp = s_up + snd*64 + c;
            ra0 = fmaf(sp[0],  MIXR(t,0) * msk, ra0);
            ra1 = fmaf(sp[16], MIXR(t,1) * msk, ra1);
            ra2 = fmaf(sp[32], MIXR(t,2) * msk, ra2);
            ra3 = fmaf(sp[48], MIXR(t,3) * msk, ra3);
        }
        float* p = agg_s + cur*128 + c;
        unsafeAtomicAdd(p,      ra0);
        unsafeAtomicAdd(p + 16, ra1);
        unsafeAtomicAdd(p + 32, ra2);
        unsafeAtomicAdd(p + 48, ra3);
    } else if (wq == 1) {     // agg_s[:, 64+ntl*16+c] += (mv.Y)/sqrt3 * mix1
        float ra0=0.f, ra1=0.f, ra2=0.f, ra3=0.f;
        #pragma unroll
        for (int t = 0; t < 16; ++t) {
            const int sl  = (lane & 48) + t;
            const int rcv = __shfl(rcv_l, sl);
            const int snd = __shfl(snd_l, sl);
            const float msk = __shfl(msk_l, sl);
            const float Y0 = __shfl(Y0_l, sl), Y1 = __shfl(Y1_l, sl), Y2 = __shfl(Y2_l, sl);
            if (rcv != cur) {
                if (cur >= 0) {
                    float* p = agg_s + cur*128 + 64 + c;
                    unsafeAtomicAdd(p,      ra0);
                    unsafeAtomicAdd(p + 16, ra1);
                    unsafeAtomicAdd(p + 32, ra2);
                    unsafeAtomicAdd(p + 48, ra3);
                }
                ra0 = ra1 = ra2 = ra3 = 0.f; cur = rcv;
            }
            const float* vp = v_up + (snd*64 + c)*3;
            const float t00 = (vp[  0]*Y0 + vp[  1]*Y1 + vp[  2]*Y2) * INV_SQRT3_F;
            const float t01 = (vp[ 48]*Y0 + vp[ 49]*Y1 + vp[ 50]*Y2) * INV_SQRT3_F;
            const float t02 = (vp[ 96]*Y0 + vp[ 97]*Y1 + vp[ 98]*Y2) * INV_SQRT3_F;
            const float t03 = (vp[144]*Y0 + vp[145]*Y1 + vp[146]*Y2) * INV_SQRT3_F;
            ra0 = fmaf(t00, MIXR(t,0) * msk, ra0);
            ra1 = fmaf(t01, MIXR(t,1) * msk, ra1);
            ra2 = fmaf(t02, MIXR(t,2) * msk, ra2);
            ra3 = fmaf(t03, MIXR(t,3) * msk, ra3);
        }
        float* p = agg_s + cur*128 + 64 + c;
        unsafeAtomicAdd(p,      ra0);
        unsafeAtomicAdd(p + 16, ra1);
        unsafeAtomicAdd(p + 32, ra2);
        unsafeAtomicAdd(p + 48, ra3);
    } else if (wq == 2) {     // agg_v[:, ntl*16+c, m] += mv_m * mix2
        float rv[4][3];
        #pragma unroll
        for (int i = 0; i < 4; ++i) { rv[i][0]=0.f; rv[i][1]=0.f; rv[i][2]=0.f; }
        #pragma unroll
        for (int t = 0; t < 16; ++t) {
            const int sl  = (lane & 48) + t;
            const int rcv = __shfl(rcv_l, sl);
            const int snd = __shfl(snd_l, sl);
            const float msk = __shfl(msk_l, sl);
            if (rcv != cur) {
                if (cur >= 0) {
                    float* p = agg_v + cur*384 + c*3;
                    #pragma unroll
                    for (int ntl = 0; ntl < 4; ++ntl)
                        #pragma unroll
                        for (int m = 0; m < 3; ++m)
                            unsafeAtomicAdd(p + ntl*48 + m, rv[ntl][m]);
                }
                #pragma unroll
                for (int i = 0; i < 4; ++i) { rv[i][0]=0.f; rv[i][1]=0.f; rv[i][2]=0.f; }
                cur = rcv;
            }
            const float* vp = v_up + (snd*64 + c)*3;
            #pragma unroll
            for (int ntl = 0; ntl < 4; ++ntl) {
                const float mx = MIXR(t,ntl) * msk;
                #pragma unroll
                for (int m = 0; m < 3; ++m)
                    rv[ntl][m] = fmaf(vp[ntl*48 + m], mx, rv[ntl][m]);
            }
        }
        float* p = agg_v + cur*384 + c*3;
        #pragma unroll
        for (int ntl = 0; ntl < 4; ++ntl)
            #pragma unroll
            for (int m = 0; m < 3; ++m)
                unsafeAtomicAdd(p + ntl*48 + m, rv[ntl][m]);
    } else {                  // agg_v[:, 64+ntl*16+c, m] += msv * Y_m * mix3
        float rv[4][3];
        #pragma unroll
        for (int i = 0; i < 4; ++i) { rv[i][0]=0.f; rv[i][1]=0.f; rv[i][2]=0.f; }
        #pragma unroll
        for (int t = 0; t < 16; ++t) {
            const int sl  = (lane & 48) + t;
            const int rcv = __shfl(rcv_l, sl);
            const int snd = __shfl(snd_l, sl);
            const float msk = __shfl(msk_l, sl);
            const float Y0 = __shfl(Y0_l, sl), Y1 = __shfl(Y1_l, sl), Y2 = __shfl(Y2_l, sl);
            if (rcv != cur) {
                if (cur >= 0) {
                    float* p = agg_v + cur*384 + 192 + c*3;
                    #pragma unroll
                    for (int ntl = 0; ntl < 4; ++ntl)
                        #pragma unroll
                        for (int m = 0; m < 3; ++m)
                            unsafeAtomicAdd(p + ntl*48 + m, rv[ntl][m]);
                }
                #pragma unroll
                for (int i = 0; i < 4; ++i) { rv[i][0]=0.f; rv[i][1]=0.f; rv[i][2]=0.f; }
                cur = rcv;
            }
            const float* sp = s_up + snd*64 + c;
            #pragma unroll
            for (int ntl = 0; ntl < 4; ++ntl) {
                const float mm = sp[ntl*16] * (MIXR(t,ntl) * msk);
                rv[ntl][0] = fmaf(mm, Y0, rv[ntl][0]);
                rv[ntl][1] = fmaf(mm, Y1, rv[ntl][1]);
                rv[ntl][2] = fmaf(mm, Y2, rv[ntl][2]);
            }
        }
        float* p = agg_v + cur*384 + 192 + c*3;
        #pragma unroll
        for (int ntl = 0; ntl < 4; ++ntl)
            #pragma unroll
            for (int m = 0; m < 3; ++m)
                unsafeAtomicAdd(p + ntl*48 + m, rv[ntl][m]);
    }
    #undef MIXR
}

// ---------------------------------------------------------------------------
// K3 v2 (WEIGHT-AMORTIZED): 4 nodes per wave. Wds/Wdv (96KB/node-wave before)
// loaded once per 4 nodes -> L2 traffic 1.9GB -> 0.48GB (~56us -> ~14us
// floor). Specie-skip weights can't be shared (random specie) and stay per
// node. ~45 live VGPRs; plain bounds. Grid: 1250 blocks x 16 nodes.
// ---------------------------------------------------------------------------
__global__ __launch_bounds__(256) void k_node_down(
    const float* __restrict__ ns, const float* __restrict__ nv,
    const int*   __restrict__ spec_idx,
    const float* __restrict__ Wds, const float* __restrict__ Wdv,
    const float* __restrict__ Wsks, const float* __restrict__ Wskv,
    const float* __restrict__ agg_s, const float* __restrict__ agg_v,
    float* __restrict__ out)
{
    const int lane = threadIdx.x & 63;
    const int wq   = __builtin_amdgcn_readfirstlane(threadIdx.x >> 6);
    const int n0   = blockIdx.x * 16 + wq * 4;   // nodes n0..n0+3

    float s0[4] = {}, s1[4] = {}, v0[4] = {}, v1[4] = {}, v2[4] = {};

    // down-projection: weights shared across the wave's 4 nodes
    const float* ar0  = agg_s + n0*128;
    const float* avr0 = agg_v + n0*384;
    for (int i = 0; i < 128; ++i) {
        const float wd0 = Wds[i*128 + lane];
        const float wd1 = Wds[i*128 + 64 + lane];
        const float wdv = Wdv[i*64 + lane];
        #pragma unroll
        for (int j = 0; j < 4; ++j) {
            const float a = ar0[j*128 + i] * INV_AVG;       // uniform -> s_load
            s0[j] = fmaf(a, wd0, s0[j]);
            s1[j] = fmaf(a, wd1, s1[j]);
            const float* avr = avr0 + j*384 + i*3;          // uniform -> s_load
            v0[j] = fmaf(avr[0] * INV_AVG, wdv, v0[j]);
            v1[j] = fmaf(avr[1] * INV_AVG, wdv, v1[j]);
            v2[j] = fmaf(avr[2] * INV_AVG, wdv, v2[j]);
        }
    }

    // specie skip + epilogue: per node (specie-dependent weights, no sharing)
    for (int j = 0; j < 4; ++j) {
        const int n    = n0 + j;
        const int spec = __builtin_amdgcn_readfirstlane(spec_idx[n]);
        const float* nsr = ns + n*64;
        const float* nvr = nv + n*192;
        const float* Ws  = Wsks + spec*8192;   // (64,128)
        const float* Wv  = Wskv + spec*4096;   // (64,64)
        for (int i = 0; i < 64; ++i) {
            const float s = nsr[i];
            s0[j] = fmaf(s, Ws[i*128 + lane], s0[j]);
            s1[j] = fmaf(s, Ws[i*128 + 64 + lane], s1[j]);
            const float wv = Wv[i*64 + lane];
            v0[j] = fmaf(nvr[i*3+0], wv, v0[j]);
            v1[j] = fmaf(nvr[i*3+1], wv, v1[j]);
            v2[j] = fmaf(nvr[i*3+2], wv, v2[j]);
        }
        const float scal = swish_f(s0[j]);
        const float gate = swish_f(s1[j]);
        out[n*256 + lane]            = scal;
        out[n*256 + 64 + lane*3 + 0] = v0[j] * gate;
        out[n*256 + 64 + lane*3 + 1] = v1[j] * gate;
        out[n*256 + 64 + lane*3 + 2] = v2[j] * gate;
    }
}

// ---------------------------------------------------------------------------
extern "C" void kernel_launch(void* const* d_in, const int* in_sizes, int n_in,
                              void* d_out, int out_size, void* d_ws, size_t ws_size,
                              hipStream_t stream)
{
    (void)in_sizes; (void)n_in; (void)out_size; (void)ws_size;

    const float* vectors      = (const float*)d_in[0];
    const float* node_scalars = (const float*)d_in[1];
    const float* node_vectors = (const float*)d_in[2];
    const int*   node_specie  = (const int*)d_in[3];
    const int*   senders      = (const int*)d_in[4];
    const int*   receivers    = (const int*)d_in[5];
    const float* W_skip_s     = (const float*)d_in[6];
    const float* W_skip_v     = (const float*)d_in[7];
    const float* W_up_s       = (const float*)d_in[8];
    const float* W_up_v       = (const float*)d_in[9];
    const float* W_mlp0       = (const float*)d_in[10];
    const float* W_mlp1       = (const float*)d_in[11];
    const float* W_mlp2       = (const float*)d_in[12];
    const float* W_down_s     = (const float*)d_in[13];
    const float* W_down_v     = (const float*)d_in[14];
    float* out = (float*)d_out;

    // workspace layout (round-2): 15,360,000 f32 + perm 320k ints.
    float* ws    = (float*)d_ws;
    float* s_up  = ws;                        // N*64   = 1,280,000 f32
    float* v_up  = s_up + 1280000;            // N*192  = 3,840,000
    float* agg_s = v_up + 3840000;            // N*128  = 2,560,000
    float* agg_v = agg_s + 2560000;           // N*384  = 7,680,000
    int*   perm  = (int*)(agg_v + 7680000);   // E ints = 320,000
    int*   cnt    = (int*)agg_s;              // aliased scratch (dead before node_up)
    int*   cursor = cnt + 20000;

    // edge counting sort by receiver
    hipLaunchKernelGGL(k_zero_cnt, dim3(79),   dim3(256),  0, stream, cnt);
    hipLaunchKernelGGL(k_hist,     dim3(1250), dim3(256),  0, stream, receivers, cnt);
    hipLaunchKernelGGL(k_scan,     dim3(1),    dim3(1024), 0, stream, cnt, cursor);
    hipLaunchKernelGGL(k_scatter,  dim3(1250), dim3(256),  0, stream, receivers, cursor, perm);

    hipLaunchKernelGGL(k_node_up, dim3(1250), dim3(256), 0, stream,
        node_scalars, node_vectors, W_up_s, W_up_v, s_up, v_up, agg_s, agg_v);
    hipLaunchKernelGGL(k_edge, dim3(5000), dim3(256), 0, stream,
        vectors, senders, receivers, perm, W_mlp0, W_mlp1, W_mlp2,
        s_up, v_up, agg_s, agg_v);
    hipLaunchKernelGGL(k_node_down, dim3(1250), dim3(256), 0, stream,
        node_scalars, node_vectors, node_specie, W_down_s, W_down_v,
        W_skip_s, W_skip_v, agg_s, agg_v, out);
}

// Round 5
// 518.946 us; speedup vs baseline: 1.3913x; 1.2205x over previous
//
#include <hip/hip_runtime.h>
#include <math.h>

// Problem constants: N=20000, E=320000, C=64, NS=4, NB=8, NH=64
#define PI_F        3.14159265358979323846f
#define SQRT2_F     1.41421356237309515f
#define SQRT3_F     1.73205080756887729f
#define INV_SQRT3_F 0.57735026918962576f
#define INV_AVG     0.25f   // 1/sqrt(16)

#define N_NODES 20000
#define N_EDGES 320000

typedef float v2f __attribute__((ext_vector_type(2)));
typedef float v4f __attribute__((ext_vector_type(4)));

__device__ __forceinline__ float swish_f(float x) {
    return x / (1.f + __expf(-x));
}

// ---------------------------------------------------------------------------
// LAUNCH-BOUNDS LAW (measured r0-r3): hipcc allocates VGPR budget =
// 256/min_waves exactly (w=4 -> 64, w=6 -> 40, w=8 -> 32) and spills whatever
// doesn't fit. k_edge live state ~90-100 regs -> only w=4 works. Small/node
// kernels (~25 live regs) fit w=8 (r3 measured: non-edge 228us, best).
// AMORTIZATION LAW (r4): trading per-lane VMEM activation streams for
// wave-uniform s_load chains regresses (scalar cache + serial latency):
// non-edge 228 -> 342us. Node kernels stay in simple per-node form.
// ---------------------------------------------------------------------------
__global__ __launch_bounds__(256, 8) void k_zero_cnt(int* __restrict__ cnt) {
    const int i = blockIdx.x * 256 + threadIdx.x;
    if (i < N_NODES) cnt[i] = 0;
}
__global__ __launch_bounds__(256, 8) void k_hist(const int* __restrict__ rcv,
                                                 int* __restrict__ cnt) {
    const int e = blockIdx.x * 256 + threadIdx.x;
    if (e < N_EDGES) atomicAdd(&cnt[rcv[e]], 1);
}
__global__ __launch_bounds__(1024) void k_scan(const int* __restrict__ cnt,
                                               int* __restrict__ cursor) {
    __shared__ int part[1024];
    const int t = threadIdx.x;
    const int base = t * 20;
    int s = 0;
    #pragma unroll
    for (int j = 0; j < 20; ++j) {
        const int idx = base + j;
        if (idx < N_NODES) s += cnt[idx];
    }
    part[t] = s;
    __syncthreads();
    for (int d = 1; d < 1024; d <<= 1) {
        const int v = (t >= d) ? part[t - d] : 0;
        __syncthreads();
        part[t] += v;
        __syncthreads();
    }
    int run = (t == 0) ? 0 : part[t - 1];
    for (int j = 0; j < 20; ++j) {
        const int idx = base + j;
        if (idx < N_NODES) { cursor[idx] = run; run += cnt[idx]; }
    }
}
__global__ __launch_bounds__(256, 8) void k_scatter(const int* __restrict__ rcv,
                                                    int* __restrict__ cursor,
                                                    int* __restrict__ perm) {
    const int e = blockIdx.x * 256 + threadIdx.x;
    if (e < N_EDGES) {
        const int pos = atomicAdd(&cursor[rcv[e]], 1);
        perm[pos] = e;
    }
}

// ---------------------------------------------------------------------------
// K1: node up-projection + agg zero-init (round-3 measured-best form:
// per-node, per-lane VMEM streams, (256,8)).
// ---------------------------------------------------------------------------
__global__ __launch_bounds__(256, 8) void k_node_up(
    const float* __restrict__ ns, const float* __restrict__ nv,
    const float* __restrict__ Wus, const float* __restrict__ Wuv,
    float* __restrict__ s_up, float* __restrict__ v_up,
    float* __restrict__ agg_s, float* __restrict__ agg_v)
{
    const int lane = threadIdx.x & 63;
    const int wq   = __builtin_amdgcn_readfirstlane(threadIdx.x >> 6);
    const int n    = blockIdx.x * 4 + wq;

    const float* nsr = ns + n * 64;
    const float* nvr = nv + n * 192;
    float acc = 0.f, a0 = 0.f, a1 = 0.f, a2 = 0.f;
    for (int i = 0; i < 64; ++i) {
        const float s = nsr[i];
        acc = fmaf(s, Wus[i*64 + lane], acc);
        const float wv = Wuv[i*64 + lane];
        a0 = fmaf(nvr[i*3+0], wv, a0);
        a1 = fmaf(nvr[i*3+1], wv, a1);
        a2 = fmaf(nvr[i*3+2], wv, a2);
    }
    s_up[n*64 + lane] = acc;
    v_up[(n*64 + lane)*3 + 0] = a0;
    v_up[(n*64 + lane)*3 + 1] = a1;
    v_up[(n*64 + lane)*3 + 2] = a2;

    agg_s[n*128 + lane]      = 0.f;
    agg_s[n*128 + 64 + lane] = 0.f;
    #pragma unroll
    for (int k = 0; k < 6; ++k) agg_v[n*384 + k*64 + lane] = 0.f;
}

// ---------------------------------------------------------------------------
// K2 v8 (MEASURED BEST, UNCHANGED): round-2 bytes, (256,4). 267-291us
// (container variance band on identical bytes). VALUBusy ~60%, Occ 40%,
// no spill, no bank conflicts.
// ---------------------------------------------------------------------------
__global__ __launch_bounds__(256, 4) void k_edge(
    const float* __restrict__ vecs,
    const int*   __restrict__ snd_idx, const int* __restrict__ rcv_idx,
    const int*   __restrict__ perm,
    const float* __restrict__ W0, const float* __restrict__ W1,
    const float* __restrict__ W2,
    const float* __restrict__ s_up, const float* __restrict__ v_up,
    float* __restrict__ agg_s, float* __restrict__ agg_v)
{
    __shared__ float hv[64*68];   // [ch][le], stride 68; holds h1 then h2

    const int tid  = threadIdx.x;
    const int lane = tid & 63;
    const int wq   = __builtin_amdgcn_readfirstlane(tid >> 6);
    const int e0   = blockIdx.x * 64;
    const int c    = lane & 15, q = lane >> 4;

    // --- per-lane metadata for sorted slot e0+lane (all 64 edges) ---
    const int pe_l  = perm[e0 + lane];
    const int rcv_l = rcv_idx[pe_l];
    const int snd_l = snd_idx[pe_l];
    const float vx_l = vecs[pe_l*3+0], vy_l = vecs[pe_l*3+1], vz_l = vecs[pe_l*3+2];
    const float x_l  = sqrtf(vx_l*vx_l + vy_l*vy_l + vz_l*vz_l);
    const float sx_l = (x_l == 0.f) ? 1.f : x_l;
    const float ys_l = SQRT3_F / sx_l;
    const float Y0_l = vx_l * ys_l, Y1_l = vy_l * ys_l, Y2_l = vz_l * ys_l;
    const float msk_l = (x_l == 0.f) ? 0.f : 1.f;

    // ---- A1: bessel + layer0 -> h1, channel=lane, edges le=wq*16+t ----
    float h1o[16];
    #pragma unroll 4
    for (int t = 0; t < 16; ++t) {
        const int le = wq*16 + t;
        const float x = __shfl(x_l, le);
        const float sx = (x == 0.f) ? 1.f : x;
        float s1, c1;
        __sincosf(PI_F * x, &s1, &c1);
        const float u  = fminf(x, 1.f);
        const float u2 = u*u, u3 = u2*u;
        const float u6 = u3*u3, u7 = u6*u, u8 = u6*u2;
        const float env  = (x < 1.f) ? (1.f - 28.f*u6 + 48.f*u7 - 21.f*u8) : 0.f;
        const float pref = SQRT2_F * env / sx;
        float h1 = 0.f;
        float sn = s1, snm1 = 0.f;
        const float twoc = 2.f * c1;
        #pragma unroll
        for (int b = 0; b < 8; ++b) {
            h1 = fmaf(pref * sn, W0[b*64 + lane], h1);
            const float snext = fmaf(twoc, sn, -snm1);
            snm1 = sn; sn = snext;
        }
        h1o[t] = swish_f(h1);
    }
    {   // write own channel-row, own wave's 16 edge-columns: 4x ds_write_b128
        float* dst = hv + lane*68 + wq*16;
        #pragma unroll
        for (int k = 0; k < 4; ++k)
            ((v4f*)dst)[k] = (v4f){h1o[4*k], h1o[4*k+1], h1o[4*k+2], h1o[4*k+3]};
    }
    // no barrier: A2 reads only columns wq*16..+15, written by this wave.

    // ---- A2: h2 = swish(h1 @ W1); reads all rows i fully, then overwrites
    //      own row (=lane) of the same columns. lane = output channel.
    {
        v2f acc2[8];
        #pragma unroll
        for (int tp = 0; tp < 8; ++tp) acc2[tp] = (v2f){0.f, 0.f};
        const float* hbase = hv + wq*16;
        for (int i = 0; i < 64; ++i) {
            const float w = W1[i*64 + lane];           // coalesced, L1-hot
            const v2f wv = {w, w};
            const v4f* hp4 = (const v4f*)(hbase + i*68);
            #pragma unroll
            for (int k = 0; k < 4; ++k) {
                const v4f h4 = hp4[k];
                const v2f hlo = __builtin_shufflevector(h4, h4, 0, 1);
                const v2f hhi = __builtin_shufflevector(h4, h4, 2, 3);
                acc2[2*k]   = __builtin_elementwise_fma(hlo, wv, acc2[2*k]);
                acc2[2*k+1] = __builtin_elementwise_fma(hhi, wv, acc2[2*k+1]);
            }
        }
        float* dst = hv + lane*68 + wq*16;
        #pragma unroll
        for (int k = 0; k < 4; ++k)
            ((v4f*)dst)[k] = (v4f){swish_f(acc2[2*k][0]),   swish_f(acc2[2*k][1]),
                                   swish_f(acc2[2*k+1][0]), swish_f(acc2[2*k+1][1])};
    }
    __syncthreads();

    // ---- B: mixp[t/2][ntl] pairs; lane (c,q) of wave wq accumulates
    //      mix[64wq + ntl*16 + c][le = q*16 + t] for t=0..15.
    v2f mixp[8][4];
    #pragma unroll
    for (int tp = 0; tp < 8; ++tp)
        #pragma unroll
        for (int j = 0; j < 4; ++j) mixp[tp][j] = (v2f){0.f, 0.f};
    {
        const float* W2c = W2 + 64*wq + c;
        const float* hq  = hv + q*16;
        for (int i = 0; i < 64; ++i) {
            const float w0 = W2c[i*256 +  0];
            const float w1 = W2c[i*256 + 16];
            const float w2 = W2c[i*256 + 32];
            const float w3 = W2c[i*256 + 48];
            const v2f w0v = {w0,w0}, w1v = {w1,w1}, w2v = {w2,w2}, w3v = {w3,w3};
            const v4f* hp4 = (const v4f*)(hq + i*68);
            #pragma unroll
            for (int k = 0; k < 4; ++k) {
                const v4f h4 = hp4[k];
                const v2f hlo = __builtin_shufflevector(h4, h4, 0, 1);
                const v2f hhi = __builtin_shufflevector(h4, h4, 2, 3);
                mixp[2*k][0]   = __builtin_elementwise_fma(hlo, w0v, mixp[2*k][0]);
                mixp[2*k][1]   = __builtin_elementwise_fma(hlo, w1v, mixp[2*k][1]);
                mixp[2*k][2]   = __builtin_elementwise_fma(hlo, w2v, mixp[2*k][2]);
                mixp[2*k][3]   = __builtin_elementwise_fma(hlo, w3v, mixp[2*k][3]);
                mixp[2*k+1][0] = __builtin_elementwise_fma(hhi, w0v, mixp[2*k+1][0]);
                mixp[2*k+1][1] = __builtin_elementwise_fma(hhi, w1v, mixp[2*k+1][1]);
                mixp[2*k+1][2] = __builtin_elementwise_fma(hhi, w2v, mixp[2*k+1][2]);
                mixp[2*k+1][3] = __builtin_elementwise_fma(hhi, w3v, mixp[2*k+1][3]);
            }
        }
    }
    #define MIXR(t,j) (mixp[(t)>>1][j][(t)&1])

    // ---- C: per-q-group segmented scatter-add from registers (v5) ----
    int cur = -1;
    if (wq == 0) {            // agg_s[:, ntl*16+c] += msv * mix0
        float ra0=0.f, ra1=0.f, ra2=0.f, ra3=0.f;
        #pragma unroll
        for (int t = 0; t < 16; ++t) {
            const int sl  = (lane & 48) + t;
            const int rcv = __shfl(rcv_l, sl);
            const int snd = __shfl(snd_l, sl);
            const float msk = __shfl(msk_l, sl);
            if (rcv != cur) {
                if (cur >= 0) {
                    float* p = agg_s + cur*128 + c;
                    unsafeAtomicAdd(p,      ra0);
                    unsafeAtomicAdd(p + 16, ra1);
                    unsafeAtomicAdd(p + 32, ra2);
                    unsafeAtomicAdd(p + 48, ra3);
                }
                ra0 = ra1 = ra2 = ra3 = 0.f; cur = rcv;
            }
            const float* sp = s_up + snd*64 + c;
            ra0 = fmaf(sp[0],  MIXR(t,0) * msk, ra0);
            ra1 = fmaf(sp[16], MIXR(t,1) * msk, ra1);
            ra2 = fmaf(sp[32], MIXR(t,2) * msk, ra2);
            ra3 = fmaf(sp[48], MIXR(t,3) * msk, ra3);
        }
        float* p = agg_s + cur*128 + c;
        unsafeAtomicAdd(p,      ra0);
        unsafeAtomicAdd(p + 16, ra1);
        unsafeAtomicAdd(p + 32, ra2);
        unsafeAtomicAdd(p + 48, ra3);
    } else if (wq == 1) {     // agg_s[:, 64+ntl*16+c] += (mv.Y)/sqrt3 * mix1
        float ra0=0.f, ra1=0.f, ra2=0.f, ra3=0.f;
        #pragma unroll
        for (int t = 0; t < 16; ++t) {
            const int sl  = (lane & 48) + t;
            const int rcv = __shfl(rcv_l, sl);
            const int snd = __shfl(snd_l, sl);
            const float msk = __shfl(msk_l, sl);
            const float Y0 = __shfl(Y0_l, sl), Y1 = __shfl(Y1_l, sl), Y2 = __shfl(Y2_l, sl);
            if (rcv != cur) {
                if (cur >= 0) {
                    float* p = agg_s + cur*128 + 64 + c;
                    unsafeAtomicAdd(p,      ra0);
                    unsafeAtomicAdd(p + 16, ra1);
                    unsafeAtomicAdd(p + 32, ra2);
                    unsafeAtomicAdd(p + 48, ra3);
                }
                ra0 = ra1 = ra2 = ra3 = 0.f; cur = rcv;
            }
            const float* vp = v_up + (snd*64 + c)*3;
            const float t00 = (vp[  0]*Y0 + vp[  1]*Y1 + vp[  2]*Y2) * INV_SQRT3_F;
            const float t01 = (vp[ 48]*Y0 + vp[ 49]*Y1 + vp[ 50]*Y2) * INV_SQRT3_F;
            const float t02 = (vp[ 96]*Y0 + vp[ 97]*Y1 + vp[ 98]*Y2) * INV_SQRT3_F;
            const float t03 = (vp[144]*Y0 + vp[145]*Y1 + vp[146]*Y2) * INV_SQRT3_F;
            ra0 = fmaf(t00, MIXR(t,0) * msk, ra0);
            ra1 = fmaf(t01, MIXR(t,1) * msk, ra1);
            ra2 = fmaf(t02, MIXR(t,2) * msk, ra2);
            ra3 = fmaf(t03, MIXR(t,3) * msk, ra3);
        }
        float* p = agg_s + cur*128 + 64 + c;
        unsafeAtomicAdd(p,      ra0);
        unsafeAtomicAdd(p + 16, ra1);
        unsafeAtomicAdd(p + 32, ra2);
        unsafeAtomicAdd(p + 48, ra3);
    } else if (wq == 2) {     // agg_v[:, ntl*16+c, m] += mv_m * mix2
        float rv[4][3];
        #pragma unroll
        for (int i = 0; i < 4; ++i) { rv[i][0]=0.f; rv[i][1]=0.f; rv[i][2]=0.f; }
        #pragma unroll
        for (int t = 0; t < 16; ++t) {
            const int sl  = (lane & 48) + t;
            const int rcv = __shfl(rcv_l, sl);
            const int snd = __shfl(snd_l, sl);
            const float msk = __shfl(msk_l, sl);
            if (rcv != cur) {
                if (cur >= 0) {
                    float* p = agg_v + cur*384 + c*3;
                    #pragma unroll
                    for (int ntl = 0; ntl < 4; ++ntl)
                        #pragma unroll
                        for (int m = 0; m < 3; ++m)
                            unsafeAtomicAdd(p + ntl*48 + m, rv[ntl][m]);
                }
                #pragma unroll
                for (int i = 0; i < 4; ++i) { rv[i][0]=0.f; rv[i][1]=0.f; rv[i][2]=0.f; }
                cur = rcv;
            }
            const float* vp = v_up + (snd*64 + c)*3;
            #pragma unroll
            for (int ntl = 0; ntl < 4; ++ntl) {
                const float mx = MIXR(t,ntl) * msk;
                #pragma unroll
                for (int m = 0; m < 3; ++m)
                    rv[ntl][m] = fmaf(vp[ntl*48 + m], mx, rv[ntl][m]);
            }
        }
        float* p = agg_v + cur*384 + c*3;
        #pragma unroll
        for (int ntl = 0; ntl < 4; ++ntl)
            #pragma unroll
            for (int m = 0; m < 3; ++m)
                unsafeAtomicAdd(p + ntl*48 + m, rv[ntl][m]);
    } else {                  // agg_v[:, 64+ntl*16+c, m] += msv * Y_m * mix3
        float rv[4][3];
        #pragma unroll
        for (int i = 0; i < 4; ++i) { rv[i][0]=0.f; rv[i][1]=0.f; rv[i][2]=0.f; }
        #pragma unroll
        for (int t = 0; t < 16; ++t) {
            const int sl  = (lane & 48) + t;
            const int rcv = __shfl(rcv_l, sl);
            const int snd = __shfl(snd_l, sl);
            const float msk = __shfl(msk_l, sl);
            const float Y0 = __shfl(Y0_l, sl), Y1 = __shfl(Y1_l, sl), Y2 = __shfl(Y2_l, sl);
            if (rcv != cur) {
                if (cur >= 0) {
                    float* p = agg_v + cur*384 + 192 + c*3;
                    #pragma unroll
                    for (int ntl = 0; ntl < 4; ++ntl)
                        #pragma unroll
                        for (int m = 0; m < 3; ++m)
                            unsafeAtomicAdd(p + ntl*48 + m, rv[ntl][m]);
                }
                #pragma unroll
                for (int i = 0; i < 4; ++i) { rv[i][0]=0.f; rv[i][1]=0.f; rv[i][2]=0.f; }
                cur = rcv;
            }
            const float* sp = s_up + snd*64 + c;
            #pragma unroll
            for (int ntl = 0; ntl < 4; ++ntl) {
                const float mm = sp[ntl*16] * (MIXR(t,ntl) * msk);
                rv[ntl][0] = fmaf(mm, Y0, rv[ntl][0]);
                rv[ntl][1] = fmaf(mm, Y1, rv[ntl][1]);
                rv[ntl][2] = fmaf(mm, Y2, rv[ntl][2]);
            }
        }
        float* p = agg_v + cur*384 + 192 + c*3;
        #pragma unroll
        for (int ntl = 0; ntl < 4; ++ntl)
            #pragma unroll
            for (int m = 0; m < 3; ++m)
                unsafeAtomicAdd(p + ntl*48 + m, rv[ntl][m]);
    }
    #undef MIXR
}

// ---------------------------------------------------------------------------
// K3: node down-projection + specie skip + swish gating (round-3 measured-best
// form: per-node, per-lane VMEM streams, (256,8)).
// ---------------------------------------------------------------------------
__global__ __launch_bounds__(256, 8) void k_node_down(
    const float* __restrict__ ns, const float* __restrict__ nv,
    const int*   __restrict__ spec_idx,
    const float* __restrict__ Wds, const float* __restrict__ Wdv,
    const float* __restrict__ Wsks, const float* __restrict__ Wskv,
    const float* __restrict__ agg_s, const float* __restrict__ agg_v,
    float* __restrict__ out)
{
    const int lane = threadIdx.x & 63;
    const int wq   = __builtin_amdgcn_readfirstlane(threadIdx.x >> 6);
    const int n    = blockIdx.x * 4 + wq;
    const int spec = __builtin_amdgcn_readfirstlane(spec_idx[n]);

    const float* ar  = agg_s + n*128;
    const float* avr = agg_v + n*384;
    float s0 = 0.f, s1 = 0.f, v0 = 0.f, v1 = 0.f, v2 = 0.f;
    for (int i = 0; i < 128; ++i) {
        const float a = ar[i] * INV_AVG;
        s0 = fmaf(a, Wds[i*128 + lane], s0);
        s1 = fmaf(a, Wds[i*128 + 64 + lane], s1);
        const float wv = Wdv[i*64 + lane];
        v0 = fmaf(avr[i*3+0] * INV_AVG, wv, v0);
        v1 = fmaf(avr[i*3+1] * INV_AVG, wv, v1);
        v2 = fmaf(avr[i*3+2] * INV_AVG, wv, v2);
    }
    const float* nsr = ns + n*64;
    const float* nvr = nv + n*192;
    const float* Ws  = Wsks + spec*8192;   // (64,128)
    const float* Wv  = Wskv + spec*4096;   // (64,64)
    for (int i = 0; i < 64; ++i) {
        const float s = nsr[i];
        s0 = fmaf(s, Ws[i*128 + lane], s0);
        s1 = fmaf(s, Ws[i*128 + 64 + lane], s1);
        const float wv = Wv[i*64 + lane];
        v0 = fmaf(nvr[i*3+0], wv, v0);
        v1 = fmaf(nvr[i*3+1], wv, v1);
        v2 = fmaf(nvr[i*3+2], wv, v2);
    }
    const float scal = swish_f(s0);
    const float gate = swish_f(s1);
    out[n*256 + lane]               = scal;
    out[n*256 + 64 + lane*3 + 0]    = v0 * gate;
    out[n*256 + 64 + lane*3 + 1]    = v1 * gate;
    out[n*256 + 64 + lane*3 + 2]    = v2 * gate;
}

// ---------------------------------------------------------------------------
extern "C" void kernel_launch(void* const* d_in, const int* in_sizes, int n_in,
                              void* d_out, int out_size, void* d_ws, size_t ws_size,
                              hipStream_t stream)
{
    (void)in_sizes; (void)n_in; (void)out_size; (void)ws_size;

    const float* vectors      = (const float*)d_in[0];
    const float* node_scalars = (const float*)d_in[1];
    const float* node_vectors = (const float*)d_in[2];
    const int*   node_specie  = (const int*)d_in[3];
    const int*   senders      = (const int*)d_in[4];
    const int*   receivers    = (const int*)d_in[5];
    const float* W_skip_s     = (const float*)d_in[6];
    const float* W_skip_v     = (const float*)d_in[7];
    const float* W_up_s       = (const float*)d_in[8];
    const float* W_up_v       = (const float*)d_in[9];
    const float* W_mlp0       = (const float*)d_in[10];
    const float* W_mlp1       = (const float*)d_in[11];
    const float* W_mlp2       = (const float*)d_in[12];
    const float* W_down_s     = (const float*)d_in[13];
    const float* W_down_v     = (const float*)d_in[14];
    float* out = (float*)d_out;

    // workspace layout (round-2): 15,360,000 f32 + perm 320k ints.
    float* ws    = (float*)d_ws;
    float* s_up  = ws;                        // N*64   = 1,280,000 f32
    float* v_up  = s_up + 1280000;            // N*192  = 3,840,000
    float* agg_s = v_up + 3840000;            // N*128  = 2,560,000
    float* agg_v = agg_s + 2560000;           // N*384  = 7,680,000
    int*   perm  = (int*)(agg_v + 7680000);   // E ints = 320,000
    int*   cnt    = (int*)agg_s;              // aliased scratch (dead before node_up)
    int*   cursor = cnt + 20000;

    // edge counting sort by receiver
    hipLaunchKernelGGL(k_zero_cnt, dim3(79),   dim3(256),  0, stream, cnt);
    hipLaunchKernelGGL(k_hist,     dim3(1250), dim3(256),  0, stream, receivers, cnt);
    hipLaunchKernelGGL(k_scan,     dim3(1),    dim3(1024), 0, stream, cnt, cursor);
    hipLaunchKernelGGL(k_scatter,  dim3(1250), dim3(256),  0, stream, receivers, cursor, perm);

    hipLaunchKernelGGL(k_node_up, dim3(5000), dim3(256), 0, stream,
        node_scalars, node_vectors, W_up_s, W_up_v, s_up, v_up, agg_s, agg_v);
    hipLaunchKernelGGL(k_edge, dim3(5000), dim3(256), 0, stream,
        vectors, senders, receivers, perm, W_mlp0, W_mlp1, W_mlp2,
        s_up, v_up, agg_s, agg_v);
    hipLaunchKernelGGL(k_node_down, dim3(5000), dim3(256), 0, stream,
        node_scalars, node_vectors, node_specie, W_down_s, W_down_v,
        W_skip_s, W_skip_v, agg_s, agg_v, out);
}

// Round 6
// 491.718 us; speedup vs baseline: 1.4683x; 1.0554x over previous
//
#include <hip/hip_runtime.h>
#include <math.h>

// Problem constants: N=20000, E=320000, C=64, NS=4, NB=8, NH=64
#define PI_F        3.14159265358979323846f
#define SQRT2_F     1.41421356237309515f
#define SQRT3_F     1.73205080756887729f
#define INV_SQRT3_F 0.57735026918962576f
#define INV_AVG     0.25f   // 1/sqrt(16)

#define N_NODES 20000
#define N_EDGES 320000

typedef float v2f __attribute__((ext_vector_type(2)));
typedef float v4f __attribute__((ext_vector_type(4)));

__device__ __forceinline__ float swish_f(float x) {
    return x / (1.f + __expf(-x));
}

// ---------------------------------------------------------------------------
// SESSION LAWS (measured r0-r5):
//  * LAUNCH-BOUNDS: hipcc allocates VGPR budget = 256/min_waves exactly
//    (w=4 -> 64, w=6 -> 40, w=8 -> 32) and spills what doesn't fit. k_edge
//    (~90-100 live regs) only works at w=4. Small kernels (<32 regs) take w=8.
//  * AMORTIZATION (r4): weight reuse across nodes MUST NOT route activations
//    through wave-uniform s_load chains (scalar cache serializes; 228->342us).
//    r6 variant: activations staged in LDS, read via uniform ds_read_b128
//    (HW broadcast); weights stay per-lane coalesced VMEM.
//  * k_edge band on identical bytes: 266-291us (container variance).
// ---------------------------------------------------------------------------
__global__ __launch_bounds__(256, 8) void k_zero_cnt(int* __restrict__ cnt) {
    const int i = blockIdx.x * 256 + threadIdx.x;
    if (i < N_NODES) cnt[i] = 0;
}
__global__ __launch_bounds__(256, 8) void k_hist(const int* __restrict__ rcv,
                                                 int* __restrict__ cnt) {
    const int e = blockIdx.x * 256 + threadIdx.x;
    if (e < N_EDGES) atomicAdd(&cnt[rcv[e]], 1);
}
__global__ __launch_bounds__(1024) void k_scan(const int* __restrict__ cnt,
                                               int* __restrict__ cursor) {
    __shared__ int part[1024];
    const int t = threadIdx.x;
    const int base = t * 20;
    int s = 0;
    #pragma unroll
    for (int j = 0; j < 20; ++j) {
        const int idx = base + j;
        if (idx < N_NODES) s += cnt[idx];
    }
    part[t] = s;
    __syncthreads();
    for (int d = 1; d < 1024; d <<= 1) {
        const int v = (t >= d) ? part[t - d] : 0;
        __syncthreads();
        part[t] += v;
        __syncthreads();
    }
    int run = (t == 0) ? 0 : part[t - 1];
    for (int j = 0; j < 20; ++j) {
        const int idx = base + j;
        if (idx < N_NODES) { cursor[idx] = run; run += cnt[idx]; }
    }
}
__global__ __launch_bounds__(256, 8) void k_scatter(const int* __restrict__ rcv,
                                                    int* __restrict__ cursor,
                                                    int* __restrict__ perm) {
    const int e = blockIdx.x * 256 + threadIdx.x;
    if (e < N_EDGES) {
        const int pos = atomicAdd(&cursor[rcv[e]], 1);
        perm[pos] = e;
    }
}

// ---------------------------------------------------------------------------
// K1 v3 (LDS-BROADCAST AMORTIZED): 16 nodes/block, 4/wave. Activations
// staged in LDS as float4{s, v0, v1, v2} per i; inner loop reads them via
// uniform ds_read_b128 broadcast. Weights Wus/Wuv loaded once per 4 nodes
// (per-lane coalesced VMEM) -> L2 weight traffic 0.64GB -> 0.16GB.
// Grid: 1250 blocks. LDS 16KB.
// ---------------------------------------------------------------------------
__global__ __launch_bounds__(256) void k_node_up(
    const float* __restrict__ ns, const float* __restrict__ nv,
    const float* __restrict__ Wus, const float* __restrict__ Wuv,
    float* __restrict__ s_up, float* __restrict__ v_up,
    float* __restrict__ agg_s, float* __restrict__ agg_v)
{
    __shared__ v4f actu[16*64];   // 16KB: [n][i] = {s_i, v_i0, v_i1, v_i2}

    const int tid  = threadIdx.x;
    const int lane = tid & 63;
    const int wq   = __builtin_amdgcn_readfirstlane(tid >> 6);
    const int nb   = blockIdx.x * 16;

    // cooperative staging: 1024 entries, 4 per thread, coalesced in i
    #pragma unroll
    for (int k = 0; k < 4; ++k) {
        const int idx = k*256 + tid;
        const int n = idx >> 6, i = idx & 63;
        const float* nvp = nv + (nb + n)*192 + 3*i;
        actu[idx] = (v4f){ns[(nb + n)*64 + i], nvp[0], nvp[1], nvp[2]};
    }
    __syncthreads();

    float acc[4] = {0.f, 0.f, 0.f, 0.f};
    float a0[4] = {}, a1[4] = {}, a2[4] = {};
    const v4f* aw = actu + wq*4*64;
    for (int i = 0; i < 64; ++i) {
        const float wu = Wus[i*64 + lane];
        const float wv = Wuv[i*64 + lane];
        #pragma unroll
        for (int j = 0; j < 4; ++j) {
            const v4f a = aw[j*64 + i];      // uniform ds_read_b128 broadcast
            acc[j] = fmaf(a.x, wu, acc[j]);
            a0[j]  = fmaf(a.y, wv, a0[j]);
            a1[j]  = fmaf(a.z, wv, a1[j]);
            a2[j]  = fmaf(a.w, wv, a2[j]);
        }
    }
    #pragma unroll
    for (int j = 0; j < 4; ++j) {
        const int n = nb + wq*4 + j;
        s_up[n*64 + lane] = acc[j];
        v_up[(n*64 + lane)*3 + 0] = a0[j];
        v_up[(n*64 + lane)*3 + 1] = a1[j];
        v_up[(n*64 + lane)*3 + 2] = a2[j];
        agg_s[n*128 + lane]      = 0.f;
        agg_s[n*128 + 64 + lane] = 0.f;
        #pragma unroll
        for (int k = 0; k < 6; ++k) agg_v[n*384 + k*64 + lane] = 0.f;
    }
}

// ---------------------------------------------------------------------------
// K2 v8 (MEASURED BEST, UNCHANGED): round-2 bytes, (256,4). 266-291us band.
// VALUBusy ~64%, Occ 40%, no spill, no bank conflicts.
// ---------------------------------------------------------------------------
__global__ __launch_bounds__(256, 4) void k_edge(
    const float* __restrict__ vecs,
    const int*   __restrict__ snd_idx, const int* __restrict__ rcv_idx,
    const int*   __restrict__ perm,
    const float* __restrict__ W0, const float* __restrict__ W1,
    const float* __restrict__ W2,
    const float* __restrict__ s_up, const float* __restrict__ v_up,
    float* __restrict__ agg_s, float* __restrict__ agg_v)
{
    __shared__ float hv[64*68];   // [ch][le], stride 68; holds h1 then h2

    const int tid  = threadIdx.x;
    const int lane = tid & 63;
    const int wq   = __builtin_amdgcn_readfirstlane(tid >> 6);
    const int e0   = blockIdx.x * 64;
    const int c    = lane & 15, q = lane >> 4;

    // --- per-lane metadata for sorted slot e0+lane (all 64 edges) ---
    const int pe_l  = perm[e0 + lane];
    const int rcv_l = rcv_idx[pe_l];
    const int snd_l = snd_idx[pe_l];
    const float vx_l = vecs[pe_l*3+0], vy_l = vecs[pe_l*3+1], vz_l = vecs[pe_l*3+2];
    const float x_l  = sqrtf(vx_l*vx_l + vy_l*vy_l + vz_l*vz_l);
    const float sx_l = (x_l == 0.f) ? 1.f : x_l;
    const float ys_l = SQRT3_F / sx_l;
    const float Y0_l = vx_l * ys_l, Y1_l = vy_l * ys_l, Y2_l = vz_l * ys_l;
    const float msk_l = (x_l == 0.f) ? 0.f : 1.f;

    // ---- A1: bessel + layer0 -> h1, channel=lane, edges le=wq*16+t ----
    float h1o[16];
    #pragma unroll 4
    for (int t = 0; t < 16; ++t) {
        const int le = wq*16 + t;
        const float x = __shfl(x_l, le);
        const float sx = (x == 0.f) ? 1.f : x;
        float s1, c1;
        __sincosf(PI_F * x, &s1, &c1);
        const float u  = fminf(x, 1.f);
        const float u2 = u*u, u3 = u2*u;
        const float u6 = u3*u3, u7 = u6*u, u8 = u6*u2;
        const float env  = (x < 1.f) ? (1.f - 28.f*u6 + 48.f*u7 - 21.f*u8) : 0.f;
        const float pref = SQRT2_F * env / sx;
        float h1 = 0.f;
        float sn = s1, snm1 = 0.f;
        const float twoc = 2.f * c1;
        #pragma unroll
        for (int b = 0; b < 8; ++b) {
            h1 = fmaf(pref * sn, W0[b*64 + lane], h1);
            const float snext = fmaf(twoc, sn, -snm1);
            snm1 = sn; sn = snext;
        }
        h1o[t] = swish_f(h1);
    }
    {   // write own channel-row, own wave's 16 edge-columns: 4x ds_write_b128
        float* dst = hv + lane*68 + wq*16;
        #pragma unroll
        for (int k = 0; k < 4; ++k)
            ((v4f*)dst)[k] = (v4f){h1o[4*k], h1o[4*k+1], h1o[4*k+2], h1o[4*k+3]};
    }
    // no barrier: A2 reads only columns wq*16..+15, written by this wave.

    // ---- A2: h2 = swish(h1 @ W1); reads all rows i fully, then overwrites
    //      own row (=lane) of the same columns. lane = output channel.
    {
        v2f acc2[8];
        #pragma unroll
        for (int tp = 0; tp < 8; ++tp) acc2[tp] = (v2f){0.f, 0.f};
        const float* hbase = hv + wq*16;
        for (int i = 0; i < 64; ++i) {
            const float w = W1[i*64 + lane];           // coalesced, L1-hot
            const v2f wv = {w, w};
            const v4f* hp4 = (const v4f*)(hbase + i*68);
            #pragma unroll
            for (int k = 0; k < 4; ++k) {
                const v4f h4 = hp4[k];
                const v2f hlo = __builtin_shufflevector(h4, h4, 0, 1);
                const v2f hhi = __builtin_shufflevector(h4, h4, 2, 3);
                acc2[2*k]   = __builtin_elementwise_fma(hlo, wv, acc2[2*k]);
                acc2[2*k+1] = __builtin_elementwise_fma(hhi, wv, acc2[2*k+1]);
            }
        }
        float* dst = hv + lane*68 + wq*16;
        #pragma unroll
        for (int k = 0; k < 4; ++k)
            ((v4f*)dst)[k] = (v4f){swish_f(acc2[2*k][0]),   swish_f(acc2[2*k][1]),
                                   swish_f(acc2[2*k+1][0]), swish_f(acc2[2*k+1][1])};
    }
    __syncthreads();

    // ---- B: mixp[t/2][ntl] pairs; lane (c,q) of wave wq accumulates
    //      mix[64wq + ntl*16 + c][le = q*16 + t] for t=0..15.
    v2f mixp[8][4];
    #pragma unroll
    for (int tp = 0; tp < 8; ++tp)
        #pragma unroll
        for (int j = 0; j < 4; ++j) mixp[tp][j] = (v2f){0.f, 0.f};
    {
        const float* W2c = W2 + 64*wq + c;
        const float* hq  = hv + q*16;
        for (int i = 0; i < 64; ++i) {
            const float w0 = W2c[i*256 +  0];
            const float w1 = W2c[i*256 + 16];
            const float w2 = W2c[i*256 + 32];
            const float w3 = W2c[i*256 + 48];
            const v2f w0v = {w0,w0}, w1v = {w1,w1}, w2v = {w2,w2}, w3v = {w3,w3};
            const v4f* hp4 = (const v4f*)(hq + i*68);
            #pragma unroll
            for (int k = 0; k < 4; ++k) {
                const v4f h4 = hp4[k];
                const v2f hlo = __builtin_shufflevector(h4, h4, 0, 1);
                const v2f hhi = __builtin_shufflevector(h4, h4, 2, 3);
                mixp[2*k][0]   = __builtin_elementwise_fma(hlo, w0v, mixp[2*k][0]);
                mixp[2*k][1]   = __builtin_elementwise_fma(hlo, w1v, mixp[2*k][1]);
                mixp[2*k][2]   = __builtin_elementwise_fma(hlo, w2v, mixp[2*k][2]);
                mixp[2*k][3]   = __builtin_elementwise_fma(hlo, w3v, mixp[2*k][3]);
                mixp[2*k+1][0] = __builtin_elementwise_fma(hhi, w0v, mixp[2*k+1][0]);
                mixp[2*k+1][1] = __builtin_elementwise_fma(hhi, w1v, mixp[2*k+1][1]);
                mixp[2*k+1][2] = __builtin_elementwise_fma(hhi, w2v, mixp[2*k+1][2]);
                mixp[2*k+1][3] = __builtin_elementwise_fma(hhi, w3v, mixp[2*k+1][3]);
            }
        }
    }
    #define MIXR(t,j) (mixp[(t)>>1][j][(t)&1])

    // ---- C: per-q-group segmented scatter-add from registers (v5) ----
    int cur = -1;
    if (wq == 0) {            // agg_s[:, ntl*16+c] += msv * mix0
        float ra0=0.f, ra1=0.f, ra2=0.f, ra3=0.f;
        #pragma unroll
        for (int t = 0; t < 16; ++t) {
            const int sl  = (lane & 48) + t;
            const int rcv = __shfl(rcv_l, sl);
            const int snd = __shfl(snd_l, sl);
            const float msk = __shfl(msk_l, sl);
            if (rcv != cur) {
                if (cur >= 0) {
                    float* p = agg_s + cur*128 + c;
                    unsafeAtomicAdd(p,      ra0);
                    unsafeAtomicAdd(p + 16, ra1);
                    unsafeAtomicAdd(p + 32, ra2);
                    unsafeAtomicAdd(p + 48, ra3);
                }
                ra0 = ra1 = ra2 = ra3 = 0.f; cur = rcv;
            }
            const float* sp = s_up + snd*64 + c;
            ra0 = fmaf(sp[0],  MIXR(t,0) * msk, ra0);
            ra1 = fmaf(sp[16], MIXR(t,1) * msk, ra1);
            ra2 = fmaf(sp[32], MIXR(t,2) * msk, ra2);
            ra3 = fmaf(sp[48], MIXR(t,3) * msk, ra3);
        }
        float* p = agg_s + cur*128 + c;
        unsafeAtomicAdd(p,      ra0);
        unsafeAtomicAdd(p + 16, ra1);
        unsafeAtomicAdd(p + 32, ra2);
        unsafeAtomicAdd(p + 48, ra3);
    } else if (wq == 1) {     // agg_s[:, 64+ntl*16+c] += (mv.Y)/sqrt3 * mix1
        float ra0=0.f, ra1=0.f, ra2=0.f, ra3=0.f;
        #pragma unroll
        for (int t = 0; t < 16; ++t) {
            const int sl  = (lane & 48) + t;
            const int rcv = __shfl(rcv_l, sl);
            const int snd = __shfl(snd_l, sl);
            const float msk = __shfl(msk_l, sl);
            const float Y0 = __shfl(Y0_l, sl), Y1 = __shfl(Y1_l, sl), Y2 = __shfl(Y2_l, sl);
            if (rcv != cur) {
                if (cur >= 0) {
                    float* p = agg_s + cur*128 + 64 + c;
                    unsafeAtomicAdd(p,      ra0);
                    unsafeAtomicAdd(p + 16, ra1);
                    unsafeAtomicAdd(p + 32, ra2);
                    unsafeAtomicAdd(p + 48, ra3);
                }
                ra0 = ra1 = ra2 = ra3 = 0.f; cur = rcv;
            }
            const float* vp = v_up + (snd*64 + c)*3;
            const float t00 = (vp[  0]*Y0 + vp[  1]*Y1 + vp[  2]*Y2) * INV_SQRT3_F;
            const float t01 = (vp[ 48]*Y0 + vp[ 49]*Y1 + vp[ 50]*Y2) * INV_SQRT3_F;
            const float t02 = (vp[ 96]*Y0 + vp[ 97]*Y1 + vp[ 98]*Y2) * INV_SQRT3_F;
            const float t03 = (vp[144]*Y0 + vp[145]*Y1 + vp[146]*Y2) * INV_SQRT3_F;
            ra0 = fmaf(t00, MIXR(t,0) * msk, ra0);
            ra1 = fmaf(t01, MIXR(t,1) * msk, ra1);
            ra2 = fmaf(t02, MIXR(t,2) * msk, ra2);
            ra3 = fmaf(t03, MIXR(t,3) * msk, ra3);
        }
        float* p = agg_s + cur*128 + 64 + c;
        unsafeAtomicAdd(p,      ra0);
        unsafeAtomicAdd(p + 16, ra1);
        unsafeAtomicAdd(p + 32, ra2);
        unsafeAtomicAdd(p + 48, ra3);
    } else if (wq == 2) {     // agg_v[:, ntl*16+c, m] += mv_m * mix2
        float rv[4][3];
        #pragma unroll
        for (int i = 0; i < 4; ++i) { rv[i][0]=0.f; rv[i][1]=0.f; rv[i][2]=0.f; }
        #pragma unroll
        for (int t = 0; t < 16; ++t) {
            const int sl  = (lane & 48) + t;
            const int rcv = __shfl(rcv_l, sl);
            const int snd = __shfl(snd_l, sl);
            const float msk = __shfl(msk_l, sl);
            if (rcv != cur) {
                if (cur >= 0) {
                    float* p = agg_v + cur*384 + c*3;
                    #pragma unroll
                    for (int ntl = 0; ntl < 4; ++ntl)
                        #pragma unroll
                        for (int m = 0; m < 3; ++m)
                            unsafeAtomicAdd(p + ntl*48 + m, rv[ntl][m]);
                }
                #pragma unroll
                for (int i = 0; i < 4; ++i) { rv[i][0]=0.f; rv[i][1]=0.f; rv[i][2]=0.f; }
                cur = rcv;
            }
            const float* vp = v_up + (snd*64 + c)*3;
            #pragma unroll
            for (int ntl = 0; ntl < 4; ++ntl) {
                const float mx = MIXR(t,ntl) * msk;
                #pragma unroll
                for (int m = 0; m < 3; ++m)
                    rv[ntl][m] = fmaf(vp[ntl*48 + m], mx, rv[ntl][m]);
            }
        }
        float* p = agg_v + cur*384 + c*3;
        #pragma unroll
        for (int ntl = 0; ntl < 4; ++ntl)
            #pragma unroll
            for (int m = 0; m < 3; ++m)
                unsafeAtomicAdd(p + ntl*48 + m, rv[ntl][m]);
    } else {                  // agg_v[:, 64+ntl*16+c, m] += msv * Y_m * mix3
        float rv[4][3];
        #pragma unroll
        for (int i = 0; i < 4; ++i) { rv[i][0]=0.f; rv[i][1]=0.f; rv[i][2]=0.f; }
        #pragma unroll
        for (int t = 0; t < 16; ++t) {
            const int sl  = (lane & 48) + t;
            const int rcv = __shfl(rcv_l, sl);
            const int snd = __shfl(snd_l, sl);
            const float msk = __shfl(msk_l, sl);
            const float Y0 = __shfl(Y0_l, sl), Y1 = __shfl(Y1_l, sl), Y2 = __shfl(Y2_l, sl);
            if (rcv != cur) {
                if (cur >= 0) {
                    float* p = agg_v + cur*384 + 192 + c*3;
                    #pragma unroll
                    for (int ntl = 0; ntl < 4; ++ntl)
                        #pragma unroll
                        for (int m = 0; m < 3; ++m)
                            unsafeAtomicAdd(p + ntl*48 + m, rv[ntl][m]);
                }
                #pragma unroll
                for (int i = 0; i < 4; ++i) { rv[i][0]=0.f; rv[i][1]=0.f; rv[i][2]=0.f; }
                cur = rcv;
            }
            const float* sp = s_up + snd*64 + c;
            #pragma unroll
            for (int ntl = 0; ntl < 4; ++ntl) {
                const float mm = sp[ntl*16] * (MIXR(t,ntl) * msk);
                rv[ntl][0] = fmaf(mm, Y0, rv[ntl][0]);
                rv[ntl][1] = fmaf(mm, Y1, rv[ntl][1]);
                rv[ntl][2] = fmaf(mm, Y2, rv[ntl][2]);
            }
        }
        float* p = agg_v + cur*384 + 192 + c*3;
        #pragma unroll
        for (int ntl = 0; ntl < 4; ++ntl)
            #pragma unroll
            for (int m = 0; m < 3; ++m)
                unsafeAtomicAdd(p + ntl*48 + m, rv[ntl][m]);
    }
    #undef MIXR
}

// ---------------------------------------------------------------------------
// K3 v3 (LDS-BROADCAST AMORTIZED): 16 nodes/block, 4/wave. Both activation
// streams staged in LDS (act: agg pre-scaled by INV_AVG; skp: ns/nv for the
// specie skip), consumed via uniform ds_read_b128 broadcast. Down-proj
// weights Wds/Wdv loaded once per 4 nodes -> L2 1.9GB -> 0.48GB; specie-skip
// weights per-node (random specie, unamortizable, 0.96GB stays). Accumulation
// order per output identical to v2 (down-proj i then skip i). LDS 48KB ->
// 3 blocks/CU (~37% occ) -- same regime k_edge sustains. Grid 1250.
// ---------------------------------------------------------------------------
__global__ __launch_bounds__(256) void k_node_down(
    const float* __restrict__ ns, const float* __restrict__ nv,
    const int*   __restrict__ spec_idx,
    const float* __restrict__ Wds, const float* __restrict__ Wdv,
    const float* __restrict__ Wsks, const float* __restrict__ Wskv,
    const float* __restrict__ agg_s, const float* __restrict__ agg_v,
    float* __restrict__ out)
{
    __shared__ v4f act[16*128];  // 32KB: [n][i] = {a, av0, av1, av2} * INV_AVG
    __shared__ v4f skp[16*64];   // 16KB: [n][i] = {s, v0, v1, v2}

    const int tid  = threadIdx.x;
    const int lane = tid & 63;
    const int wq   = __builtin_amdgcn_readfirstlane(tid >> 6);
    const int nb   = blockIdx.x * 16;

    // stage agg (2048 entries, 8/thread) and ns/nv (1024 entries, 4/thread)
    #pragma unroll
    for (int k = 0; k < 8; ++k) {
        const int idx = k*256 + tid;
        const int n = idx >> 7, i = idx & 127;
        const float a = agg_s[(nb + n)*128 + i] * INV_AVG;
        const float* av = agg_v + (nb + n)*384 + 3*i;
        act[idx] = (v4f){a, av[0]*INV_AVG, av[1]*INV_AVG, av[2]*INV_AVG};
    }
    #pragma unroll
    for (int k = 0; k < 4; ++k) {
        const int idx = k*256 + tid;
        const int n = idx >> 6, i = idx & 63;
        const float* nvp = nv + (nb + n)*192 + 3*i;
        skp[idx] = (v4f){ns[(nb + n)*64 + i], nvp[0], nvp[1], nvp[2]};
    }
    __syncthreads();

    float s0[4] = {}, s1[4] = {}, v0[4] = {}, v1[4] = {}, v2[4] = {};

    // down-projection: weights shared across the wave's 4 nodes
    const v4f* aw = act + wq*4*128;
    for (int i = 0; i < 128; ++i) {
        const float wd0 = Wds[i*128 + lane];
        const float wd1 = Wds[i*128 + 64 + lane];
        const float wdv = Wdv[i*64 + lane];
        #pragma unroll
        for (int j = 0; j < 4; ++j) {
            const v4f a = aw[j*128 + i];     // uniform ds_read_b128 broadcast
            s0[j] = fmaf(a.x, wd0, s0[j]);
            s1[j] = fmaf(a.x, wd1, s1[j]);
            v0[j] = fmaf(a.y, wdv, v0[j]);
            v1[j] = fmaf(a.z, wdv, v1[j]);
            v2[j] = fmaf(a.w, wdv, v2[j]);
        }
    }

    // specie skip: per-node weight streams (4 independent), LDS activations
    const int n0 = nb + wq*4;
    const float* Ws_j[4]; const float* Wv_j[4];
    #pragma unroll
    for (int j = 0; j < 4; ++j) {
        const int spec = __builtin_amdgcn_readfirstlane(spec_idx[n0 + j]);
        Ws_j[j] = Wsks + spec*8192;   // (64,128)
        Wv_j[j] = Wskv + spec*4096;   // (64,64)
    }
    const v4f* sw = skp + wq*4*64;
    for (int i = 0; i < 64; ++i) {
        #pragma unroll
        for (int j = 0; j < 4; ++j) {
            const v4f a = sw[j*64 + i];      // uniform ds_read_b128 broadcast
            s0[j] = fmaf(a.x, Ws_j[j][i*128 + lane], s0[j]);
            s1[j] = fmaf(a.x, Ws_j[j][i*128 + 64 + lane], s1[j]);
            const float wv = Wv_j[j][i*64 + lane];
            v0[j] = fmaf(a.y, wv, v0[j]);
            v1[j] = fmaf(a.z, wv, v1[j]);
            v2[j] = fmaf(a.w, wv, v2[j]);
        }
    }

    #pragma unroll
    for (int j = 0; j < 4; ++j) {
        const int n = n0 + j;
        const float scal = swish_f(s0[j]);
        const float gate = swish_f(s1[j]);
        out[n*256 + lane]            = scal;
        out[n*256 + 64 + lane*3 + 0] = v0[j] * gate;
        out[n*256 + 64 + lane*3 + 1] = v1[j] * gate;
        out[n*256 + 64 + lane*3 + 2] = v2[j] * gate;
    }
}

// ---------------------------------------------------------------------------
extern "C" void kernel_launch(void* const* d_in, const int* in_sizes, int n_in,
                              void* d_out, int out_size, void* d_ws, size_t ws_size,
                              hipStream_t stream)
{
    (void)in_sizes; (void)n_in; (void)out_size; (void)ws_size;

    const float* vectors      = (const float*)d_in[0];
    const float* node_scalars = (const float*)d_in[1];
    const float* node_vectors = (const float*)d_in[2];
    const int*   node_specie  = (const int*)d_in[3];
    const int*   senders      = (const int*)d_in[4];
    const int*   receivers    = (const int*)d_in[5];
    const float* W_skip_s     = (const float*)d_in[6];
    const float* W_skip_v     = (const float*)d_in[7];
    const float* W_up_s       = (const float*)d_in[8];
    const float* W_up_v       = (const float*)d_in[9];
    const float* W_mlp0       = (const float*)d_in[10];
    const float* W_mlp1       = (const float*)d_in[11];
    const float* W_mlp2       = (const float*)d_in[12];
    const float* W_down_s     = (const float*)d_in[13];
    const float* W_down_v     = (const float*)d_in[14];
    float* out = (float*)d_out;

    // workspace layout (round-2): 15,360,000 f32 + perm 320k ints.
    float* ws    = (float*)d_ws;
    float* s_up  = ws;                        // N*64   = 1,280,000 f32
    float* v_up  = s_up + 1280000;            // N*192  = 3,840,000
    float* agg_s = v_up + 3840000;            // N*128  = 2,560,000
    float* agg_v = agg_s + 2560000;           // N*384  = 7,680,000
    int*   perm  = (int*)(agg_v + 7680000);   // E ints = 320,000
    int*   cnt    = (int*)agg_s;              // aliased scratch (dead before node_up)
    int*   cursor = cnt + 20000;

    // edge counting sort by receiver
    hipLaunchKernelGGL(k_zero_cnt, dim3(79),   dim3(256),  0, stream, cnt);
    hipLaunchKernelGGL(k_hist,     dim3(1250), dim3(256),  0, stream, receivers, cnt);
    hipLaunchKernelGGL(k_scan,     dim3(1),    dim3(1024), 0, stream, cnt, cursor);
    hipLaunchKernelGGL(k_scatter,  dim3(1250), dim3(256),  0, stream, receivers, cursor, perm);

    hipLaunchKernelGGL(k_node_up, dim3(1250), dim3(256), 0, stream,
        node_scalars, node_vectors, W_up_s, W_up_v, s_up, v_up, agg_s, agg_v);
    hipLaunchKernelGGL(k_edge, dim3(5000), dim3(256), 0, stream,
        vectors, senders, receivers, perm, W_mlp0, W_mlp1, W_mlp2,
        s_up, v_up, agg_s, agg_v);
    hipLaunchKernelGGL(k_node_down, dim3(1250), dim3(256), 0, stream,
        node_scalars, node_vectors, node_specie, W_down_s, W_down_v,
        W_skip_s, W_skip_v, agg_s, agg_v, out);
}

// Round 8
// 489.390 us; speedup vs baseline: 1.4753x; 1.0048x over previous
//
#include <hip/hip_runtime.h>
#include <math.h>

// Problem constants: N=20000, E=320000, C=64, NS=4, NB=8, NH=64
#define PI_F        3.14159265358979323846f
#define SQRT2_F     1.41421356237309515f
#define SQRT3_F     1.73205080756887729f
#define INV_SQRT3_F 0.57735026918962576f
#define INV_AVG     0.25f   // 1/sqrt(16)

#define N_NODES 20000
#define N_EDGES 320000

typedef float v2f __attribute__((ext_vector_type(2)));
typedef float v4f __attribute__((ext_vector_type(4)));

__device__ __forceinline__ float swish_f(float x) {
    return x / (1.f + __expf(-x));
}

// ---------------------------------------------------------------------------
// SESSION LAWS (measured r0-r6):
//  * LAUNCH-BOUNDS: hipcc allocates VGPR budget = 256/min_waves exactly
//    (w=4 -> 64, w=6 -> 40, w=8 -> 32) and spills what doesn't fit. k_edge
//    (~90-100 live regs) only works at w=4. Small kernels (<32 regs) take w=8.
//  * AMORTIZATION: weight reuse across nodes must NOT route activations
//    through s_load chains (r4: 228->342us). LDS staging + uniform
//    ds_read_b128 broadcast works (r6: non-edge 252->225us).
//  * k_edge band on identical bytes: 266-291us (container variance).
//  * r7 (infra-failed, resubmitted r8 without the hipMemsetAsync rider —
//    ONLY launched kernels in kernel_launch, no runtime memops):
//    quad-transposed s_up/v_up so phase-C gathers are contiguous per lane
//    (VMEM instrs 128->32/wave).
//      s_upq[n*64  + c*4  + ntl]       = s_up_old[n][ntl*16+c]
//      v_upq[n*192 + c*12 + ntl*3 + m] = v_up_old[n][ntl*16+c][m]
// ---------------------------------------------------------------------------
__global__ __launch_bounds__(256, 8) void k_zero_cnt(int* __restrict__ cnt) {
    const int i = blockIdx.x * 256 + threadIdx.x;
    if (i < N_NODES) cnt[i] = 0;
}
__global__ __launch_bounds__(256, 8) void k_hist(const int* __restrict__ rcv,
                                                 int* __restrict__ cnt) {
    const int e = blockIdx.x * 256 + threadIdx.x;
    if (e < N_EDGES) atomicAdd(&cnt[rcv[e]], 1);
}
__global__ __launch_bounds__(1024) void k_scan(const int* __restrict__ cnt,
                                               int* __restrict__ cursor) {
    __shared__ int part[1024];
    const int t = threadIdx.x;
    const int base = t * 20;
    int s = 0;
    #pragma unroll
    for (int j = 0; j < 20; ++j) {
        const int idx = base + j;
        if (idx < N_NODES) s += cnt[idx];
    }
    part[t] = s;
    __syncthreads();
    for (int d = 1; d < 1024; d <<= 1) {
        const int v = (t >= d) ? part[t - d] : 0;
        __syncthreads();
        part[t] += v;
        __syncthreads();
    }
    int run = (t == 0) ? 0 : part[t - 1];
    for (int j = 0; j < 20; ++j) {
        const int idx = base + j;
        if (idx < N_NODES) { cursor[idx] = run; run += cnt[idx]; }
    }
}
__global__ __launch_bounds__(256, 8) void k_scatter(const int* __restrict__ rcv,
                                                    int* __restrict__ cursor,
                                                    int* __restrict__ perm) {
    const int e = blockIdx.x * 256 + threadIdx.x;
    if (e < N_EDGES) {
        const int pos = atomicAdd(&cursor[rcv[e]], 1);
        perm[pos] = e;
    }
}

// ---------------------------------------------------------------------------
// K1 v4: LDS-broadcast amortized (r6 structure) + quad-transposed epilogue
// writes for s_up/v_up (r7 layout). Grid 1250, LDS 16KB.
// ---------------------------------------------------------------------------
__global__ __launch_bounds__(256) void k_node_up(
    const float* __restrict__ ns, const float* __restrict__ nv,
    const float* __restrict__ Wus, const float* __restrict__ Wuv,
    float* __restrict__ s_up, float* __restrict__ v_up,
    float* __restrict__ agg_s, float* __restrict__ agg_v)
{
    __shared__ v4f actu[16*64];   // 16KB: [n][i] = {s_i, v_i0, v_i1, v_i2}

    const int tid  = threadIdx.x;
    const int lane = tid & 63;
    const int wq   = __builtin_amdgcn_readfirstlane(tid >> 6);
    const int nb   = blockIdx.x * 16;

    // cooperative staging: 1024 entries, 4 per thread, coalesced in i
    #pragma unroll
    for (int k = 0; k < 4; ++k) {
        const int idx = k*256 + tid;
        const int n = idx >> 6, i = idx & 63;
        const float* nvp = nv + (nb + n)*192 + 3*i;
        actu[idx] = (v4f){ns[(nb + n)*64 + i], nvp[0], nvp[1], nvp[2]};
    }
    __syncthreads();

    float acc[4] = {0.f, 0.f, 0.f, 0.f};
    float a0[4] = {}, a1[4] = {}, a2[4] = {};
    const v4f* aw = actu + wq*4*64;
    for (int i = 0; i < 64; ++i) {
        const float wu = Wus[i*64 + lane];
        const float wv = Wuv[i*64 + lane];
        #pragma unroll
        for (int j = 0; j < 4; ++j) {
            const v4f a = aw[j*64 + i];      // uniform ds_read_b128 broadcast
            acc[j] = fmaf(a.x, wu, acc[j]);
            a0[j]  = fmaf(a.y, wv, a0[j]);
            a1[j]  = fmaf(a.z, wv, a1[j]);
            a2[j]  = fmaf(a.w, wv, a2[j]);
        }
    }
    const int cc = lane & 15, nt = lane >> 4;   // channel = nt*16 + cc
    #pragma unroll
    for (int j = 0; j < 4; ++j) {
        const int n = nb + wq*4 + j;
        s_up[n*64 + cc*4 + nt] = acc[j];             // quad-transposed
        float* vq = v_up + n*192 + cc*12 + nt*3;     // quad-transposed
        vq[0] = a0[j]; vq[1] = a1[j]; vq[2] = a2[j];
        agg_s[n*128 + lane]      = 0.f;
        agg_s[n*128 + 64 + lane] = 0.f;
        #pragma unroll
        for (int k = 0; k < 6; ++k) agg_v[n*384 + k*64 + lane] = 0.f;
    }
}

// ---------------------------------------------------------------------------
// K2 v10 (PHASE-C VECTOR GATHERS): identical to measured-best v8 except
// phase C reads s_up/v_up in the quad-transposed layout: per t-step,
// wq0/wq3 do ONE dwordx4 (was 4 dwords), wq1/wq2 THREE dwordx4 (was 12
// dwords). Same bytes (q-group already consumed whole sender rows), same
// math order -> same absmax. ~96 fewer VMEM issues + 4x shorter load
// chains per wave in the latency-dominated phase.
// ---------------------------------------------------------------------------
__global__ __launch_bounds__(256, 4) void k_edge(
    const float* __restrict__ vecs,
    const int*   __restrict__ snd_idx, const int* __restrict__ rcv_idx,
    const int*   __restrict__ perm,
    const float* __restrict__ W0, const float* __restrict__ W1,
    const float* __restrict__ W2,
    const float* __restrict__ s_up, const float* __restrict__ v_up,
    float* __restrict__ agg_s, float* __restrict__ agg_v)
{
    __shared__ float hv[64*68];   // [ch][le], stride 68; holds h1 then h2

    const int tid  = threadIdx.x;
    const int lane = tid & 63;
    const int wq   = __builtin_amdgcn_readfirstlane(tid >> 6);
    const int e0   = blockIdx.x * 64;
    const int c    = lane & 15, q = lane >> 4;

    // --- per-lane metadata for sorted slot e0+lane (all 64 edges) ---
    const int pe_l  = perm[e0 + lane];
    const int rcv_l = rcv_idx[pe_l];
    const int snd_l = snd_idx[pe_l];
    const float vx_l = vecs[pe_l*3+0], vy_l = vecs[pe_l*3+1], vz_l = vecs[pe_l*3+2];
    const float x_l  = sqrtf(vx_l*vx_l + vy_l*vy_l + vz_l*vz_l);
    const float sx_l = (x_l == 0.f) ? 1.f : x_l;
    const float ys_l = SQRT3_F / sx_l;
    const float Y0_l = vx_l * ys_l, Y1_l = vy_l * ys_l, Y2_l = vz_l * ys_l;
    const float msk_l = (x_l == 0.f) ? 0.f : 1.f;

    // ---- A1: bessel + layer0 -> h1, channel=lane, edges le=wq*16+t ----
    float h1o[16];
    #pragma unroll 4
    for (int t = 0; t < 16; ++t) {
        const int le = wq*16 + t;
        const float x = __shfl(x_l, le);
        const float sx = (x == 0.f) ? 1.f : x;
        float s1, c1;
        __sincosf(PI_F * x, &s1, &c1);
        const float u  = fminf(x, 1.f);
        const float u2 = u*u, u3 = u2*u;
        const float u6 = u3*u3, u7 = u6*u, u8 = u6*u2;
        const float env  = (x < 1.f) ? (1.f - 28.f*u6 + 48.f*u7 - 21.f*u8) : 0.f;
        const float pref = SQRT2_F * env / sx;
        float h1 = 0.f;
        float sn = s1, snm1 = 0.f;
        const float twoc = 2.f * c1;
        #pragma unroll
        for (int b = 0; b < 8; ++b) {
            h1 = fmaf(pref * sn, W0[b*64 + lane], h1);
            const float snext = fmaf(twoc, sn, -snm1);
            snm1 = sn; sn = snext;
        }
        h1o[t] = swish_f(h1);
    }
    {   // write own channel-row, own wave's 16 edge-columns: 4x ds_write_b128
        float* dst = hv + lane*68 + wq*16;
        #pragma unroll
        for (int k = 0; k < 4; ++k)
            ((v4f*)dst)[k] = (v4f){h1o[4*k], h1o[4*k+1], h1o[4*k+2], h1o[4*k+3]};
    }
    // no barrier: A2 reads only columns wq*16..+15, written by this wave.

    // ---- A2: h2 = swish(h1 @ W1); reads all rows i fully, then overwrites
    //      own row (=lane) of the same columns. lane = output channel.
    {
        v2f acc2[8];
        #pragma unroll
        for (int tp = 0; tp < 8; ++tp) acc2[tp] = (v2f){0.f, 0.f};
        const float* hbase = hv + wq*16;
        for (int i = 0; i < 64; ++i) {
            const float w = W1[i*64 + lane];           // coalesced, L1-hot
            const v2f wv = {w, w};
            const v4f* hp4 = (const v4f*)(hbase + i*68);
            #pragma unroll
            for (int k = 0; k < 4; ++k) {
                const v4f h4 = hp4[k];
                const v2f hlo = __builtin_shufflevector(h4, h4, 0, 1);
                const v2f hhi = __builtin_shufflevector(h4, h4, 2, 3);
                acc2[2*k]   = __builtin_elementwise_fma(hlo, wv, acc2[2*k]);
                acc2[2*k+1] = __builtin_elementwise_fma(hhi, wv, acc2[2*k+1]);
            }
        }
        float* dst = hv + lane*68 + wq*16;
        #pragma unroll
        for (int k = 0; k < 4; ++k)
            ((v4f*)dst)[k] = (v4f){swish_f(acc2[2*k][0]),   swish_f(acc2[2*k][1]),
                                   swish_f(acc2[2*k+1][0]), swish_f(acc2[2*k+1][1])};
    }
    __syncthreads();

    // ---- B: mixp[t/2][ntl] pairs; lane (c,q) of wave wq accumulates
    //      mix[64wq + ntl*16 + c][le = q*16 + t] for t=0..15.
    v2f mixp[8][4];
    #pragma unroll
    for (int tp = 0; tp < 8; ++tp)
        #pragma unroll
        for (int j = 0; j < 4; ++j) mixp[tp][j] = (v2f){0.f, 0.f};
    {
        const float* W2c = W2 + 64*wq + c;
        const float* hq  = hv + q*16;
        for (int i = 0; i < 64; ++i) {
            const float w0 = W2c[i*256 +  0];
            const float w1 = W2c[i*256 + 16];
            const float w2 = W2c[i*256 + 32];
            const float w3 = W2c[i*256 + 48];
            const v2f w0v = {w0,w0}, w1v = {w1,w1}, w2v = {w2,w2}, w3v = {w3,w3};
            const v4f* hp4 = (const v4f*)(hq + i*68);
            #pragma unroll
            for (int k = 0; k < 4; ++k) {
                const v4f h4 = hp4[k];
                const v2f hlo = __builtin_shufflevector(h4, h4, 0, 1);
                const v2f hhi = __builtin_shufflevector(h4, h4, 2, 3);
                mixp[2*k][0]   = __builtin_elementwise_fma(hlo, w0v, mixp[2*k][0]);
                mixp[2*k][1]   = __builtin_elementwise_fma(hlo, w1v, mixp[2*k][1]);
                mixp[2*k][2]   = __builtin_elementwise_fma(hlo, w2v, mixp[2*k][2]);
                mixp[2*k][3]   = __builtin_elementwise_fma(hlo, w3v, mixp[2*k][3]);
                mixp[2*k+1][0] = __builtin_elementwise_fma(hhi, w0v, mixp[2*k+1][0]);
                mixp[2*k+1][1] = __builtin_elementwise_fma(hhi, w1v, mixp[2*k+1][1]);
                mixp[2*k+1][2] = __builtin_elementwise_fma(hhi, w2v, mixp[2*k+1][2]);
                mixp[2*k+1][3] = __builtin_elementwise_fma(hhi, w3v, mixp[2*k+1][3]);
            }
        }
    }
    #define MIXR(t,j) (mixp[(t)>>1][j][(t)&1])

    // ---- C: per-q-group segmented scatter-add from registers ----
    // quad-transposed reads: sv = s_upq[snd][c][0..3]; f0/f1/f2 = v_upq[snd][c][0..11]
    int cur = -1;
    if (wq == 0) {            // agg_s[:, ntl*16+c] += msv * mix0
        float ra0=0.f, ra1=0.f, ra2=0.f, ra3=0.f;
        #pragma unroll
        for (int t = 0; t < 16; ++t) {
            const int sl  = (lane & 48) + t;
            const int rcv = __shfl(rcv_l, sl);
            const int snd = __shfl(snd_l, sl);
            const float msk = __shfl(msk_l, sl);
            if (rcv != cur) {
                if (cur >= 0) {
                    float* p = agg_s + cur*128 + c;
                    unsafeAtomicAdd(p,      ra0);
                    unsafeAtomicAdd(p + 16, ra1);
                    unsafeAtomicAdd(p + 32, ra2);
                    unsafeAtomicAdd(p + 48, ra3);
                }
                ra0 = ra1 = ra2 = ra3 = 0.f; cur = rcv;
            }
            const v4f sv = *(const v4f*)(s_up + snd*64 + c*4);  // 1x dwordx4
            ra0 = fmaf(sv.x, MIXR(t,0) * msk, ra0);
            ra1 = fmaf(sv.y, MIXR(t,1) * msk, ra1);
            ra2 = fmaf(sv.z, MIXR(t,2) * msk, ra2);
            ra3 = fmaf(sv.w, MIXR(t,3) * msk, ra3);
        }
        float* p = agg_s + cur*128 + c;
        unsafeAtomicAdd(p,      ra0);
        unsafeAtomicAdd(p + 16, ra1);
        unsafeAtomicAdd(p + 32, ra2);
        unsafeAtomicAdd(p + 48, ra3);
    } else if (wq == 1) {     // agg_s[:, 64+ntl*16+c] += (mv.Y)/sqrt3 * mix1
        float ra0=0.f, ra1=0.f, ra2=0.f, ra3=0.f;
        #pragma unroll
        for (int t = 0; t < 16; ++t) {
            const int sl  = (lane & 48) + t;
            const int rcv = __shfl(rcv_l, sl);
            const int snd = __shfl(snd_l, sl);
            const float msk = __shfl(msk_l, sl);
            const float Y0 = __shfl(Y0_l, sl), Y1 = __shfl(Y1_l, sl), Y2 = __shfl(Y2_l, sl);
            if (rcv != cur) {
                if (cur >= 0) {
                    float* p = agg_s + cur*128 + 64 + c;
                    unsafeAtomicAdd(p,      ra0);
                    unsafeAtomicAdd(p + 16, ra1);
                    unsafeAtomicAdd(p + 32, ra2);
                    unsafeAtomicAdd(p + 48, ra3);
                }
                ra0 = ra1 = ra2 = ra3 = 0.f; cur = rcv;
            }
            const float* vb = v_up + snd*192 + c*12;
            const v4f f0 = *(const v4f*)(vb);       // 3x dwordx4
            const v4f f1 = *(const v4f*)(vb + 4);
            const v4f f2 = *(const v4f*)(vb + 8);
            const float t00 = (f0.x*Y0 + f0.y*Y1 + f0.z*Y2) * INV_SQRT3_F;
            const float t01 = (f0.w*Y0 + f1.x*Y1 + f1.y*Y2) * INV_SQRT3_F;
            const float t02 = (f1.z*Y0 + f1.w*Y1 + f2.x*Y2) * INV_SQRT3_F;
            const float t03 = (f2.y*Y0 + f2.z*Y1 + f2.w*Y2) * INV_SQRT3_F;
            ra0 = fmaf(t00, MIXR(t,0) * msk, ra0);
            ra1 = fmaf(t01, MIXR(t,1) * msk, ra1);
            ra2 = fmaf(t02, MIXR(t,2) * msk, ra2);
            ra3 = fmaf(t03, MIXR(t,3) * msk, ra3);
        }
        float* p = agg_s + cur*128 + 64 + c;
        unsafeAtomicAdd(p,      ra0);
        unsafeAtomicAdd(p + 16, ra1);
        unsafeAtomicAdd(p + 32, ra2);
        unsafeAtomicAdd(p + 48, ra3);
    } else if (wq == 2) {     // agg_v[:, ntl*16+c, m] += mv_m * mix2
        float rv[4][3];
        #pragma unroll
        for (int i = 0; i < 4; ++i) { rv[i][0]=0.f; rv[i][1]=0.f; rv[i][2]=0.f; }
        #pragma unroll
        for (int t = 0; t < 16; ++t) {
            const int sl  = (lane & 48) + t;
            const int rcv = __shfl(rcv_l, sl);
            const int snd = __shfl(snd_l, sl);
            const float msk = __shfl(msk_l, sl);
            if (rcv != cur) {
                if (cur >= 0) {
                    float* p = agg_v + cur*384 + c*3;
                    #pragma unroll
                    for (int ntl = 0; ntl < 4; ++ntl)
                        #pragma unroll
                        for (int m = 0; m < 3; ++m)
                            unsafeAtomicAdd(p + ntl*48 + m, rv[ntl][m]);
                }
                #pragma unroll
                for (int i = 0; i < 4; ++i) { rv[i][0]=0.f; rv[i][1]=0.f; rv[i][2]=0.f; }
                cur = rcv;
            }
            const float* vb = v_up + snd*192 + c*12;
            const v4f f0 = *(const v4f*)(vb);       // 3x dwordx4
            const v4f f1 = *(const v4f*)(vb + 4);
            const v4f f2 = *(const v4f*)(vb + 8);
            const float mx0 = MIXR(t,0) * msk;
            const float mx1 = MIXR(t,1) * msk;
            const float mx2 = MIXR(t,2) * msk;
            const float mx3 = MIXR(t,3) * msk;
            rv[0][0] = fmaf(f0.x, mx0, rv[0][0]);
            rv[0][1] = fmaf(f0.y, mx0, rv[0][1]);
            rv[0][2] = fmaf(f0.z, mx0, rv[0][2]);
            rv[1][0] = fmaf(f0.w, mx1, rv[1][0]);
            rv[1][1] = fmaf(f1.x, mx1, rv[1][1]);
            rv[1][2] = fmaf(f1.y, mx1, rv[1][2]);
            rv[2][0] = fmaf(f1.z, mx2, rv[2][0]);
            rv[2][1] = fmaf(f1.w, mx2, rv[2][1]);
            rv[2][2] = fmaf(f2.x, mx2, rv[2][2]);
            rv[3][0] = fmaf(f2.y, mx3, rv[3][0]);
            rv[3][1] = fmaf(f2.z, mx3, rv[3][1]);
            rv[3][2] = fmaf(f2.w, mx3, rv[3][2]);
        }
        float* p = agg_v + cur*384 + c*3;
        #pragma unroll
        for (int ntl = 0; ntl < 4; ++ntl)
            #pragma unroll
            for (int m = 0; m < 3; ++m)
                unsafeAtomicAdd(p + ntl*48 + m, rv[ntl][m]);
    } else {                  // agg_v[:, 64+ntl*16+c, m] += msv * Y_m * mix3
        float rv[4][3];
        #pragma unroll
        for (int i = 0; i < 4; ++i) { rv[i][0]=0.f; rv[i][1]=0.f; rv[i][2]=0.f; }
        #pragma unroll
        for (int t = 0; t < 16; ++t) {
            const int sl  = (lane & 48) + t;
            const int rcv = __shfl(rcv_l, sl);
            const int snd = __shfl(snd_l, sl);
            const float msk = __shfl(msk_l, sl);
            const float Y0 = __shfl(Y0_l, sl), Y1 = __shfl(Y1_l, sl), Y2 = __shfl(Y2_l, sl);
            if (rcv != cur) {
                if (cur >= 0) {
                    float* p = agg_v + cur*384 + 192 + c*3;
                    #pragma unroll
                    for (int ntl = 0; ntl < 4; ++ntl)
                        #pragma unroll
                        for (int m = 0; m < 3; ++m)
                            unsafeAtomicAdd(p + ntl*48 + m, rv[ntl][m]);
                }
                #pragma unroll
                for (int i = 0; i < 4; ++i) { rv[i][0]=0.f; rv[i][1]=0.f; rv[i][2]=0.f; }
                cur = rcv;
            }
            const v4f sv = *(const v4f*)(s_up + snd*64 + c*4);  // 1x dwordx4
            const float mm0 = sv.x * (MIXR(t,0) * msk);
            const float mm1 = sv.y * (MIXR(t,1) * msk);
            const float mm2 = sv.z * (MIXR(t,2) * msk);
            const float mm3 = sv.w * (MIXR(t,3) * msk);
            rv[0][0] = fmaf(mm0, Y0, rv[0][0]);
            rv[0][1] = fmaf(mm0, Y1, rv[0][1]);
            rv[0][2] = fmaf(mm0, Y2, rv[0][2]);
            rv[1][0] = fmaf(mm1, Y0, rv[1][0]);
            rv[1][1] = fmaf(mm1, Y1, rv[1][1]);
            rv[1][2] = fmaf(mm1, Y2, rv[1][2]);
            rv[2][0] = fmaf(mm2, Y0, rv[2][0]);
            rv[2][1] = fmaf(mm2, Y1, rv[2][1]);
            rv[2][2] = fmaf(mm2, Y2, rv[2][2]);
            rv[3][0] = fmaf(mm3, Y0, rv[3][0]);
            rv[3][1] = fmaf(mm3, Y1, rv[3][1]);
            rv[3][2] = fmaf(mm3, Y2, rv[3][2]);
        }
        float* p = agg_v + cur*384 + 192 + c*3;
        #pragma unroll
        for (int ntl = 0; ntl < 4; ++ntl)
            #pragma unroll
            for (int m = 0; m < 3; ++m)
                unsafeAtomicAdd(p + ntl*48 + m, rv[ntl][m]);
    }
    #undef MIXR
}

// ---------------------------------------------------------------------------
// K3 v3 (LDS-BROADCAST AMORTIZED, unchanged from r6 measured-best).
// ---------------------------------------------------------------------------
__global__ __launch_bounds__(256) void k_node_down(
    const float* __restrict__ ns, const float* __restrict__ nv,
    const int*   __restrict__ spec_idx,
    const float* __restrict__ Wds, const float* __restrict__ Wdv,
    const float* __restrict__ Wsks, const float* __restrict__ Wskv,
    const float* __restrict__ agg_s, const float* __restrict__ agg_v,
    float* __restrict__ out)
{
    __shared__ v4f act[16*128];  // 32KB: [n][i] = {a, av0, av1, av2} * INV_AVG
    __shared__ v4f skp[16*64];   // 16KB: [n][i] = {s, v0, v1, v2}

    const int tid  = threadIdx.x;
    const int lane = tid & 63;
    const int wq   = __builtin_amdgcn_readfirstlane(tid >> 6);
    const int nb   = blockIdx.x * 16;

    // stage agg (2048 entries, 8/thread) and ns/nv (1024 entries, 4/thread)
    #pragma unroll
    for (int k = 0; k < 8; ++k) {
        const int idx = k*256 + tid;
        const int n = idx >> 7, i = idx & 127;
        const float a = agg_s[(nb + n)*128 + i] * INV_AVG;
        const float* av = agg_v + (nb + n)*384 + 3*i;
        act[idx] = (v4f){a, av[0]*INV_AVG, av[1]*INV_AVG, av[2]*INV_AVG};
    }
    #pragma unroll
    for (int k = 0; k < 4; ++k) {
        const int idx = k*256 + tid;
        const int n = idx >> 6, i = idx & 63;
        const float* nvp = nv + (nb + n)*192 + 3*i;
        skp[idx] = (v4f){ns[(nb + n)*64 + i], nvp[0], nvp[1], nvp[2]};
    }
    __syncthreads();

    float s0[4] = {}, s1[4] = {}, v0[4] = {}, v1[4] = {}, v2[4] = {};

    // down-projection: weights shared across the wave's 4 nodes
    const v4f* aw = act + wq*4*128;
    for (int i = 0; i < 128; ++i) {
        const float wd0 = Wds[i*128 + lane];
        const float wd1 = Wds[i*128 + 64 + lane];
        const float wdv = Wdv[i*64 + lane];
        #pragma unroll
        for (int j = 0; j < 4; ++j) {
            const v4f a = aw[j*128 + i];     // uniform ds_read_b128 broadcast
            s0[j] = fmaf(a.x, wd0, s0[j]);
            s1[j] = fmaf(a.x, wd1, s1[j]);
            v0[j] = fmaf(a.y, wdv, v0[j]);
            v1[j] = fmaf(a.z, wdv, v1[j]);
            v2[j] = fmaf(a.w, wdv, v2[j]);
        }
    }

    // specie skip: per-node weight streams (4 independent), LDS activations
    const int n0 = nb + wq*4;
    const float* Ws_j[4]; const float* Wv_j[4];
    #pragma unroll
    for (int j = 0; j < 4; ++j) {
        const int spec = __builtin_amdgcn_readfirstlane(spec_idx[n0 + j]);
        Ws_j[j] = Wsks + spec*8192;   // (64,128)
        Wv_j[j] = Wskv + spec*4096;   // (64,64)
    }
    const v4f* sw = skp + wq*4*64;
    for (int i = 0; i < 64; ++i) {
        #pragma unroll
        for (int j = 0; j < 4; ++j) {
            const v4f a = sw[j*64 + i];      // uniform ds_read_b128 broadcast
            s0[j] = fmaf(a.x, Ws_j[j][i*128 + lane], s0[j]);
            s1[j] = fmaf(a.x, Ws_j[j][i*128 + 64 + lane], s1[j]);
            const float wv = Wv_j[j][i*64 + lane];
            v0[j] = fmaf(a.y, wv, v0[j]);
            v1[j] = fmaf(a.z, wv, v1[j]);
            v2[j] = fmaf(a.w, wv, v2[j]);
        }
    }

    #pragma unroll
    for (int j = 0; j < 4; ++j) {
        const int n = n0 + j;
        const float scal = swish_f(s0[j]);
        const float gate = swish_f(s1[j]);
        out[n*256 + lane]            = scal;
        out[n*256 + 64 + lane*3 + 0] = v0[j] * gate;
        out[n*256 + 64 + lane*3 + 1] = v1[j] * gate;
        out[n*256 + 64 + lane*3 + 2] = v2[j] * gate;
    }
}

// ---------------------------------------------------------------------------
extern "C" void kernel_launch(void* const* d_in, const int* in_sizes, int n_in,
                              void* d_out, int out_size, void* d_ws, size_t ws_size,
                              hipStream_t stream)
{
    (void)in_sizes; (void)n_in; (void)out_size; (void)ws_size;

    const float* vectors      = (const float*)d_in[0];
    const float* node_scalars = (const float*)d_in[1];
    const float* node_vectors = (const float*)d_in[2];
    const int*   node_specie  = (const int*)d_in[3];
    const int*   senders      = (const int*)d_in[4];
    const int*   receivers    = (const int*)d_in[5];
    const float* W_skip_s     = (const float*)d_in[6];
    const float* W_skip_v     = (const float*)d_in[7];
    const float* W_up_s       = (const float*)d_in[8];
    const float* W_up_v       = (const float*)d_in[9];
    const float* W_mlp0       = (const float*)d_in[10];
    const float* W_mlp1       = (const float*)d_in[11];
    const float* W_mlp2       = (const float*)d_in[12];
    const float* W_down_s     = (const float*)d_in[13];
    const float* W_down_v     = (const float*)d_in[14];
    float* out = (float*)d_out;

    // workspace layout: 15,360,000 f32 + perm 320k ints.
    float* ws    = (float*)d_ws;
    float* s_up  = ws;                        // N*64   = 1,280,000 f32 (quad-T)
    float* v_up  = s_up + 1280000;            // N*192  = 3,840,000    (quad-T)
    float* agg_s = v_up + 3840000;            // N*128  = 2,560,000
    float* agg_v = agg_s + 2560000;           // N*384  = 7,680,000
    int*   perm  = (int*)(agg_v + 7680000);   // E ints = 320,000
    int*   cnt    = (int*)agg_s;              // aliased scratch (dead before node_up)
    int*   cursor = cnt + 20000;

    // edge counting sort by receiver (k_zero_cnt kernel restored: kernels
    // only in kernel_launch — r7's hipMemsetAsync rider removed after the
    // container/graph-capture failure, to keep the experiment unconfounded)
    hipLaunchKernelGGL(k_zero_cnt, dim3(79),   dim3(256),  0, stream, cnt);
    hipLaunchKernelGGL(k_hist,     dim3(1250), dim3(256),  0, stream, receivers, cnt);
    hipLaunchKernelGGL(k_scan,     dim3(1),    dim3(1024), 0, stream, cnt, cursor);
    hipLaunchKernelGGL(k_scatter,  dim3(1250), dim3(256),  0, stream, receivers, cursor, perm);

    hipLaunchKernelGGL(k_node_up, dim3(1250), dim3(256), 0, stream,
        node_scalars, node_vectors, W_up_s, W_up_v, s_up, v_up, agg_s, agg_v);
    hipLaunchKernelGGL(k_edge, dim3(5000), dim3(256), 0, stream,
        vectors, senders, receivers, perm, W_mlp0, W_mlp1, W_mlp2,
        s_up, v_up, agg_s, agg_v);
    hipLaunchKernelGGL(k_node_down, dim3(1250), dim3(256), 0, stream,
        node_scalars, node_vectors, node_specie, W_down_s, W_down_v,
        W_skip_s, W_skip_v, agg_s, agg_v, out);
}

// Round 9
// 485.768 us; speedup vs baseline: 1.4863x; 1.0075x over previous
//
#include <hip/hip_runtime.h>
#include <math.h>

// Problem constants: N=20000, E=320000, C=64, NS=4, NB=8, NH=64
#define PI_F        3.14159265358979323846f
#define SQRT2_F     1.41421356237309515f
#define SQRT3_F     1.73205080756887729f
#define INV_SQRT3_F 0.57735026918962576f
#define INV_AVG     0.25f   // 1/sqrt(16)

#define N_NODES 20000
#define N_EDGES 320000

typedef float v2f __attribute__((ext_vector_type(2)));
typedef float v4f __attribute__((ext_vector_type(4)));

__device__ __forceinline__ float swish_f(float x) {
    return x / (1.f + __expf(-x));
}

// ---------------------------------------------------------------------------
// SESSION LAWS (measured r0-r8):
//  * LAUNCH-BOUNDS: hipcc allocates VGPR budget = 256/min_waves exactly
//    (w=4 -> 64, w=6 -> 40, w=8 -> 32) and spills what doesn't fit. k_edge
//    only works at w=4. Small kernels (<32 regs) take w=8.
//  * AMORTIZATION: weight reuse across nodes must NOT route activations
//    through s_load chains (r4). LDS staging + uniform ds_read_b128
//    broadcast works (r6).
//  * kernel_launch must contain ONLY kernel launches (r7's hipMemsetAsync
//    coincided with a graph-capture/container failure; r8 without it ran).
//  * r8: phase-C VMEM issue cut (quad-transpose) = only +1.5% -> k_edge is
//    VALU-stream + phase-C-serialization bound, not VMEM-issue bound.
//  * k_edge band on identical bytes: 262-291us (container variance).
//  * r9: (a) A1 per-lane sincos dedup + pref-folded mask (bit-identical,
//    ~1k fewer VALU cyc/wave); (b) node_down block-local specie grouping.
// ---------------------------------------------------------------------------
__global__ __launch_bounds__(256, 8) void k_zero_cnt(int* __restrict__ cnt) {
    const int i = blockIdx.x * 256 + threadIdx.x;
    if (i < N_NODES) cnt[i] = 0;
}
__global__ __launch_bounds__(256, 8) void k_hist(const int* __restrict__ rcv,
                                                 int* __restrict__ cnt) {
    const int e = blockIdx.x * 256 + threadIdx.x;
    if (e < N_EDGES) atomicAdd(&cnt[rcv[e]], 1);
}
__global__ __launch_bounds__(1024) void k_scan(const int* __restrict__ cnt,
                                               int* __restrict__ cursor) {
    __shared__ int part[1024];
    const int t = threadIdx.x;
    const int base = t * 20;
    int s = 0;
    #pragma unroll
    for (int j = 0; j < 20; ++j) {
        const int idx = base + j;
        if (idx < N_NODES) s += cnt[idx];
    }
    part[t] = s;
    __syncthreads();
    for (int d = 1; d < 1024; d <<= 1) {
        const int v = (t >= d) ? part[t - d] : 0;
        __syncthreads();
        part[t] += v;
        __syncthreads();
    }
    int run = (t == 0) ? 0 : part[t - 1];
    for (int j = 0; j < 20; ++j) {
        const int idx = base + j;
        if (idx < N_NODES) { cursor[idx] = run; run += cnt[idx]; }
    }
}
__global__ __launch_bounds__(256, 8) void k_scatter(const int* __restrict__ rcv,
                                                    int* __restrict__ cursor,
                                                    int* __restrict__ perm) {
    const int e = blockIdx.x * 256 + threadIdx.x;
    if (e < N_EDGES) {
        const int pos = atomicAdd(&cursor[rcv[e]], 1);
        perm[pos] = e;
    }
}

// ---------------------------------------------------------------------------
// K1 v4: LDS-broadcast amortized + quad-transposed epilogue (r8 measured).
// ---------------------------------------------------------------------------
__global__ __launch_bounds__(256) void k_node_up(
    const float* __restrict__ ns, const float* __restrict__ nv,
    const float* __restrict__ Wus, const float* __restrict__ Wuv,
    float* __restrict__ s_up, float* __restrict__ v_up,
    float* __restrict__ agg_s, float* __restrict__ agg_v)
{
    __shared__ v4f actu[16*64];   // 16KB: [n][i] = {s_i, v_i0, v_i1, v_i2}

    const int tid  = threadIdx.x;
    const int lane = tid & 63;
    const int wq   = __builtin_amdgcn_readfirstlane(tid >> 6);
    const int nb   = blockIdx.x * 16;

    #pragma unroll
    for (int k = 0; k < 4; ++k) {
        const int idx = k*256 + tid;
        const int n = idx >> 6, i = idx & 63;
        const float* nvp = nv + (nb + n)*192 + 3*i;
        actu[idx] = (v4f){ns[(nb + n)*64 + i], nvp[0], nvp[1], nvp[2]};
    }
    __syncthreads();

    float acc[4] = {0.f, 0.f, 0.f, 0.f};
    float a0[4] = {}, a1[4] = {}, a2[4] = {};
    const v4f* aw = actu + wq*4*64;
    for (int i = 0; i < 64; ++i) {
        const float wu = Wus[i*64 + lane];
        const float wv = Wuv[i*64 + lane];
        #pragma unroll
        for (int j = 0; j < 4; ++j) {
            const v4f a = aw[j*64 + i];      // uniform ds_read_b128 broadcast
            acc[j] = fmaf(a.x, wu, acc[j]);
            a0[j]  = fmaf(a.y, wv, a0[j]);
            a1[j]  = fmaf(a.z, wv, a1[j]);
            a2[j]  = fmaf(a.w, wv, a2[j]);
        }
    }
    const int cc = lane & 15, nt = lane >> 4;   // channel = nt*16 + cc
    #pragma unroll
    for (int j = 0; j < 4; ++j) {
        const int n = nb + wq*4 + j;
        s_up[n*64 + cc*4 + nt] = acc[j];             // quad-transposed
        float* vq = v_up + n*192 + cc*12 + nt*3;     // quad-transposed
        vq[0] = a0[j]; vq[1] = a1[j]; vq[2] = a2[j];
        agg_s[n*128 + lane]      = 0.f;
        agg_s[n*128 + 64 + lane] = 0.f;
        #pragma unroll
        for (int k = 0; k < 6; ++k) agg_v[n*384 + k*64 + lane] = 0.f;
    }
}

// ---------------------------------------------------------------------------
// K2 v11 (A1 DEDUP + MASK FOLD): r8 structure, but
//  * A1: sincos/env/pref computed ONCE per lane for its own edge, t-loop
//    shuffles the 3 scalars (bit-identical: same x input). pref folded
//    after the 8-fma sum (8 mults -> 1/t).
//  * pref=0 for x==0 edges => h1=0 => h2=swish(0)=0 => mix==0, so the msk
//    shuffle + 4 multiplies per t-step are deleted from all phase-C branches.
// ---------------------------------------------------------------------------
__global__ __launch_bounds__(256, 4) void k_edge(
    const float* __restrict__ vecs,
    const int*   __restrict__ snd_idx, const int* __restrict__ rcv_idx,
    const int*   __restrict__ perm,
    const float* __restrict__ W0, const float* __restrict__ W1,
    const float* __restrict__ W2,
    const float* __restrict__ s_up, const float* __restrict__ v_up,
    float* __restrict__ agg_s, float* __restrict__ agg_v)
{
    __shared__ float hv[64*68];   // [ch][le], stride 68; holds h1 then h2

    const int tid  = threadIdx.x;
    const int lane = tid & 63;
    const int wq   = __builtin_amdgcn_readfirstlane(tid >> 6);
    const int e0   = blockIdx.x * 64;
    const int c    = lane & 15, q = lane >> 4;

    // --- per-lane metadata for sorted slot e0+lane (all 64 edges) ---
    const int pe_l  = perm[e0 + lane];
    const int rcv_l = rcv_idx[pe_l];
    const int snd_l = snd_idx[pe_l];
    const float vx_l = vecs[pe_l*3+0], vy_l = vecs[pe_l*3+1], vz_l = vecs[pe_l*3+2];
    const float x_l  = sqrtf(vx_l*vx_l + vy_l*vy_l + vz_l*vz_l);
    const float sx_l = (x_l == 0.f) ? 1.f : x_l;
    const float ys_l = SQRT3_F / sx_l;
    const float Y0_l = vx_l * ys_l, Y1_l = vy_l * ys_l, Y2_l = vz_l * ys_l;

    // per-lane bessel scalars for OWN edge (computed once, shuffled in A1)
    float s1_l, c1_l;
    __sincosf(PI_F * x_l, &s1_l, &c1_l);
    float pref_l;
    {
        const float u  = fminf(x_l, 1.f);
        const float u2 = u*u, u3 = u2*u;
        const float u6 = u3*u3, u7 = u6*u, u8 = u6*u2;
        const float env = (x_l < 1.f) ? (1.f - 28.f*u6 + 48.f*u7 - 21.f*u8) : 0.f;
        // mask folded: x==0 edges force pref=0 -> h1=0 -> h2=0 -> mix==0
        pref_l = (x_l == 0.f) ? 0.f : (SQRT2_F * env / sx_l);
    }

    // ---- A1: bessel + layer0 -> h1, channel=lane, edges le=wq*16+t ----
    float h1o[16];
    #pragma unroll 4
    for (int t = 0; t < 16; ++t) {
        const int le = wq*16 + t;
        const float sn0  = __shfl(s1_l, le);
        const float twoc = 2.f * __shfl(c1_l, le);
        const float pref = __shfl(pref_l, le);
        float acc1 = 0.f;
        float sn = sn0, snm1 = 0.f;
        #pragma unroll
        for (int b = 0; b < 8; ++b) {
            acc1 = fmaf(sn, W0[b*64 + lane], acc1);
            const float snext = fmaf(twoc, sn, -snm1);
            snm1 = sn; sn = snext;
        }
        h1o[t] = swish_f(pref * acc1);
    }
    {   // write own channel-row, own wave's 16 edge-columns: 4x ds_write_b128
        float* dst = hv + lane*68 + wq*16;
        #pragma unroll
        for (int k = 0; k < 4; ++k)
            ((v4f*)dst)[k] = (v4f){h1o[4*k], h1o[4*k+1], h1o[4*k+2], h1o[4*k+3]};
    }
    // no barrier: A2 reads only columns wq*16..+15, written by this wave.

    // ---- A2: h2 = swish(h1 @ W1); reads all rows i fully, then overwrites
    //      own row (=lane) of the same columns. lane = output channel.
    {
        v2f acc2[8];
        #pragma unroll
        for (int tp = 0; tp < 8; ++tp) acc2[tp] = (v2f){0.f, 0.f};
        const float* hbase = hv + wq*16;
        for (int i = 0; i < 64; ++i) {
            const float w = W1[i*64 + lane];           // coalesced, L1-hot
            const v2f wv = {w, w};
            const v4f* hp4 = (const v4f*)(hbase + i*68);
            #pragma unroll
            for (int k = 0; k < 4; ++k) {
                const v4f h4 = hp4[k];
                const v2f hlo = __builtin_shufflevector(h4, h4, 0, 1);
                const v2f hhi = __builtin_shufflevector(h4, h4, 2, 3);
                acc2[2*k]   = __builtin_elementwise_fma(hlo, wv, acc2[2*k]);
                acc2[2*k+1] = __builtin_elementwise_fma(hhi, wv, acc2[2*k+1]);
            }
        }
        float* dst = hv + lane*68 + wq*16;
        #pragma unroll
        for (int k = 0; k < 4; ++k)
            ((v4f*)dst)[k] = (v4f){swish_f(acc2[2*k][0]),   swish_f(acc2[2*k][1]),
                                   swish_f(acc2[2*k+1][0]), swish_f(acc2[2*k+1][1])};
    }
    __syncthreads();

    // ---- B: mixp[t/2][ntl] pairs; lane (c,q) of wave wq accumulates
    //      mix[64wq + ntl*16 + c][le = q*16 + t] for t=0..15.
    v2f mixp[8][4];
    #pragma unroll
    for (int tp = 0; tp < 8; ++tp)
        #pragma unroll
        for (int j = 0; j < 4; ++j) mixp[tp][j] = (v2f){0.f, 0.f};
    {
        const float* W2c = W2 + 64*wq + c;
        const float* hq  = hv + q*16;
        for (int i = 0; i < 64; ++i) {
            const float w0 = W2c[i*256 +  0];
            const float w1 = W2c[i*256 + 16];
            const float w2 = W2c[i*256 + 32];
            const float w3 = W2c[i*256 + 48];
            const v2f w0v = {w0,w0}, w1v = {w1,w1}, w2v = {w2,w2}, w3v = {w3,w3};
            const v4f* hp4 = (const v4f*)(hq + i*68);
            #pragma unroll
            for (int k = 0; k < 4; ++k) {
                const v4f h4 = hp4[k];
                const v2f hlo = __builtin_shufflevector(h4, h4, 0, 1);
                const v2f hhi = __builtin_shufflevector(h4, h4, 2, 3);
                mixp[2*k][0]   = __builtin_elementwise_fma(hlo, w0v, mixp[2*k][0]);
                mixp[2*k][1]   = __builtin_elementwise_fma(hlo, w1v, mixp[2*k][1]);
                mixp[2*k][2]   = __builtin_elementwise_fma(hlo, w2v, mixp[2*k][2]);
                mixp[2*k][3]   = __builtin_elementwise_fma(hlo, w3v, mixp[2*k][3]);
                mixp[2*k+1][0] = __builtin_elementwise_fma(hhi, w0v, mixp[2*k+1][0]);
                mixp[2*k+1][1] = __builtin_elementwise_fma(hhi, w1v, mixp[2*k+1][1]);
                mixp[2*k+1][2] = __builtin_elementwise_fma(hhi, w2v, mixp[2*k+1][2]);
                mixp[2*k+1][3] = __builtin_elementwise_fma(hhi, w3v, mixp[2*k+1][3]);
            }
        }
    }
    #define MIXR(t,j) (mixp[(t)>>1][j][(t)&1])

    // ---- C: per-q-group segmented scatter-add from registers ----
    // quad-transposed reads; mix already carries the zero-length mask.
    int cur = -1;
    if (wq == 0) {            // agg_s[:, ntl*16+c] += msv * mix0
        float ra0=0.f, ra1=0.f, ra2=0.f, ra3=0.f;
        #pragma unroll
        for (int t = 0; t < 16; ++t) {
            const int sl  = (lane & 48) + t;
            const int rcv = __shfl(rcv_l, sl);
            const int snd = __shfl(snd_l, sl);
            if (rcv != cur) {
                if (cur >= 0) {
                    float* p = agg_s + cur*128 + c;
                    unsafeAtomicAdd(p,      ra0);
                    unsafeAtomicAdd(p + 16, ra1);
                    unsafeAtomicAdd(p + 32, ra2);
                    unsafeAtomicAdd(p + 48, ra3);
                }
                ra0 = ra1 = ra2 = ra3 = 0.f; cur = rcv;
            }
            const v4f sv = *(const v4f*)(s_up + snd*64 + c*4);  // 1x dwordx4
            ra0 = fmaf(sv.x, MIXR(t,0), ra0);
            ra1 = fmaf(sv.y, MIXR(t,1), ra1);
            ra2 = fmaf(sv.z, MIXR(t,2), ra2);
            ra3 = fmaf(sv.w, MIXR(t,3), ra3);
        }
        float* p = agg_s + cur*128 + c;
        unsafeAtomicAdd(p,      ra0);
        unsafeAtomicAdd(p + 16, ra1);
        unsafeAtomicAdd(p + 32, ra2);
        unsafeAtomicAdd(p + 48, ra3);
    } else if (wq == 1) {     // agg_s[:, 64+ntl*16+c] += (mv.Y)/sqrt3 * mix1
        float ra0=0.f, ra1=0.f, ra2=0.f, ra3=0.f;
        #pragma unroll
        for (int t = 0; t < 16; ++t) {
            const int sl  = (lane & 48) + t;
            const int rcv = __shfl(rcv_l, sl);
            const int snd = __shfl(snd_l, sl);
            const float Y0 = __shfl(Y0_l, sl), Y1 = __shfl(Y1_l, sl), Y2 = __shfl(Y2_l, sl);
            if (rcv != cur) {
                if (cur >= 0) {
                    float* p = agg_s + cur*128 + 64 + c;
                    unsafeAtomicAdd(p,      ra0);
                    unsafeAtomicAdd(p + 16, ra1);
                    unsafeAtomicAdd(p + 32, ra2);
                    unsafeAtomicAdd(p + 48, ra3);
                }
                ra0 = ra1 = ra2 = ra3 = 0.f; cur = rcv;
            }
            const float* vb = v_up + snd*192 + c*12;
            const v4f f0 = *(const v4f*)(vb);       // 3x dwordx4
            const v4f f1 = *(const v4f*)(vb + 4);
            const v4f f2 = *(const v4f*)(vb + 8);
            const float t00 = (f0.x*Y0 + f0.y*Y1 + f0.z*Y2) * INV_SQRT3_F;
            const float t01 = (f0.w*Y0 + f1.x*Y1 + f1.y*Y2) * INV_SQRT3_F;
            const float t02 = (f1.z*Y0 + f1.w*Y1 + f2.x*Y2) * INV_SQRT3_F;
            const float t03 = (f2.y*Y0 + f2.z*Y1 + f2.w*Y2) * INV_SQRT3_F;
            ra0 = fmaf(t00, MIXR(t,0), ra0);
            ra1 = fmaf(t01, MIXR(t,1), ra1);
            ra2 = fmaf(t02, MIXR(t,2), ra2);
            ra3 = fmaf(t03, MIXR(t,3), ra3);
        }
        float* p = agg_s + cur*128 + 64 + c;
        unsafeAtomicAdd(p,      ra0);
        unsafeAtomicAdd(p + 16, ra1);
        unsafeAtomicAdd(p + 32, ra2);
        unsafeAtomicAdd(p + 48, ra3);
    } else if (wq == 2) {     // agg_v[:, ntl*16+c, m] += mv_m * mix2
        float rv[4][3];
        #pragma unroll
        for (int i = 0; i < 4; ++i) { rv[i][0]=0.f; rv[i][1]=0.f; rv[i][2]=0.f; }
        #pragma unroll
        for (int t = 0; t < 16; ++t) {
            const int sl  = (lane & 48) + t;
            const int rcv = __shfl(rcv_l, sl);
            const int snd = __shfl(snd_l, sl);
            if (rcv != cur) {
                if (cur >= 0) {
                    float* p = agg_v + cur*384 + c*3;
                    #pragma unroll
                    for (int ntl = 0; ntl < 4; ++ntl)
                        #pragma unroll
                        for (int m = 0; m < 3; ++m)
                            unsafeAtomicAdd(p + ntl*48 + m, rv[ntl][m]);
                }
                #pragma unroll
                for (int i = 0; i < 4; ++i) { rv[i][0]=0.f; rv[i][1]=0.f; rv[i][2]=0.f; }
                cur = rcv;
            }
            const float* vb = v_up + snd*192 + c*12;
            const v4f f0 = *(const v4f*)(vb);       // 3x dwordx4
            const v4f f1 = *(const v4f*)(vb + 4);
            const v4f f2 = *(const v4f*)(vb + 8);
            const float mx0 = MIXR(t,0);
            const float mx1 = MIXR(t,1);
            const float mx2 = MIXR(t,2);
            const float mx3 = MIXR(t,3);
            rv[0][0] = fmaf(f0.x, mx0, rv[0][0]);
            rv[0][1] = fmaf(f0.y, mx0, rv[0][1]);
            rv[0][2] = fmaf(f0.z, mx0, rv[0][2]);
            rv[1][0] = fmaf(f0.w, mx1, rv[1][0]);
            rv[1][1] = fmaf(f1.x, mx1, rv[1][1]);
            rv[1][2] = fmaf(f1.y, mx1, rv[1][2]);
            rv[2][0] = fmaf(f1.z, mx2, rv[2][0]);
            rv[2][1] = fmaf(f1.w, mx2, rv[2][1]);
            rv[2][2] = fmaf(f2.x, mx2, rv[2][2]);
            rv[3][0] = fmaf(f2.y, mx3, rv[3][0]);
            rv[3][1] = fmaf(f2.z, mx3, rv[3][1]);
            rv[3][2] = fmaf(f2.w, mx3, rv[3][2]);
        }
        float* p = agg_v + cur*384 + c*3;
        #pragma unroll
        for (int ntl = 0; ntl < 4; ++ntl)
            #pragma unroll
            for (int m = 0; m < 3; ++m)
                unsafeAtomicAdd(p + ntl*48 + m, rv[ntl][m]);
    } else {                  // agg_v[:, 64+ntl*16+c, m] += msv * Y_m * mix3
        float rv[4][3];
        #pragma unroll
        for (int i = 0; i < 4; ++i) { rv[i][0]=0.f; rv[i][1]=0.f; rv[i][2]=0.f; }
        #pragma unroll
        for (int t = 0; t < 16; ++t) {
            const int sl  = (lane & 48) + t;
            const int rcv = __shfl(rcv_l, sl);
            const int snd = __shfl(snd_l, sl);
            const float Y0 = __shfl(Y0_l, sl), Y1 = __shfl(Y1_l, sl), Y2 = __shfl(Y2_l, sl);
            if (rcv != cur) {
                if (cur >= 0) {
                    float* p = agg_v + cur*384 + 192 + c*3;
                    #pragma unroll
                    for (int ntl = 0; ntl < 4; ++ntl)
                        #pragma unroll
                        for (int m = 0; m < 3; ++m)
                            unsafeAtomicAdd(p + ntl*48 + m, rv[ntl][m]);
                }
                #pragma unroll
                for (int i = 0; i < 4; ++i) { rv[i][0]=0.f; rv[i][1]=0.f; rv[i][2]=0.f; }
                cur = rcv;
            }
            const v4f sv = *(const v4f*)(s_up + snd*64 + c*4);  // 1x dwordx4
            const float mm0 = sv.x * MIXR(t,0);
            const float mm1 = sv.y * MIXR(t,1);
            const float mm2 = sv.z * MIXR(t,2);
            const float mm3 = sv.w * MIXR(t,3);
            rv[0][0] = fmaf(mm0, Y0, rv[0][0]);
            rv[0][1] = fmaf(mm0, Y1, rv[0][1]);
            rv[0][2] = fmaf(mm0, Y2, rv[0][2]);
            rv[1][0] = fmaf(mm1, Y0, rv[1][0]);
            rv[1][1] = fmaf(mm1, Y1, rv[1][1]);
            rv[1][2] = fmaf(mm1, Y2, rv[1][2]);
            rv[2][0] = fmaf(mm2, Y0, rv[2][0]);
            rv[2][1] = fmaf(mm2, Y1, rv[2][1]);
            rv[2][2] = fmaf(mm2, Y2, rv[2][2]);
            rv[3][0] = fmaf(mm3, Y0, rv[3][0]);
            rv[3][1] = fmaf(mm3, Y1, rv[3][1]);
            rv[3][2] = fmaf(mm3, Y2, rv[3][2]);
        }
        float* p = agg_v + cur*384 + 192 + c*3;
        #pragma unroll
        for (int ntl = 0; ntl < 4; ++ntl)
            #pragma unroll
            for (int m = 0; m < 3; ++m)
                unsafeAtomicAdd(p + ntl*48 + m, rv[ntl][m]);
    }
    #undef MIXR
}

// ---------------------------------------------------------------------------
// K3 v4 (SPECIE-GROUPED WAVES): r6 LDS-broadcast structure + block-local
// specie ordering. The block's 16 nodes are rank-sorted by specie into
// bord[16]; wave wq processes bord[4wq..4wq+3] -> same-specie runs, so the
// 4 specie-skip weight streams per wave collapse to 1-2 distinct streams
// (L1 absorbs duplicates; L2 skip traffic ~0.96GB -> ~0.4GB). Per-node math
// order and output locations unchanged -> bit-identical.
// ---------------------------------------------------------------------------
__global__ __launch_bounds__(256) void k_node_down(
    const float* __restrict__ ns, const float* __restrict__ nv,
    const int*   __restrict__ spec_idx,
    const float* __restrict__ Wds, const float* __restrict__ Wdv,
    const float* __restrict__ Wsks, const float* __restrict__ Wskv,
    const float* __restrict__ agg_s, const float* __restrict__ agg_v,
    float* __restrict__ out)
{
    __shared__ v4f act[16*128];  // 32KB: [n][i] = {a, av0, av1, av2} * INV_AVG
    __shared__ v4f skp[16*64];   // 16KB: [n][i] = {s, v0, v1, v2}
    __shared__ int bord[16];     // block-local node order, sorted by specie

    const int tid  = threadIdx.x;
    const int lane = tid & 63;
    const int wq   = __builtin_amdgcn_readfirstlane(tid >> 6);
    const int nb   = blockIdx.x * 16;

    // rank-sort the block's 16 nodes by (specie, index) -- bijective ranks
    if (tid < 16) {
        const int sp = spec_idx[nb + tid];
        int rank = 0;
        for (int j = 0; j < 16; ++j) {
            const int spj = spec_idx[nb + j];
            if (spj < sp || (spj == sp && j < tid)) ++rank;
        }
        bord[rank] = tid;
    }

    // stage agg (2048 entries, 8/thread) and ns/nv (1024 entries, 4/thread)
    #pragma unroll
    for (int k = 0; k < 8; ++k) {
        const int idx = k*256 + tid;
        const int n = idx >> 7, i = idx & 127;
        const float a = agg_s[(nb + n)*128 + i] * INV_AVG;
        const float* av = agg_v + (nb + n)*384 + 3*i;
        act[idx] = (v4f){a, av[0]*INV_AVG, av[1]*INV_AVG, av[2]*INV_AVG};
    }
    #pragma unroll
    for (int k = 0; k < 4; ++k) {
        const int idx = k*256 + tid;
        const int n = idx >> 6, i = idx & 63;
        const float* nvp = nv + (nb + n)*192 + 3*i;
        skp[idx] = (v4f){ns[(nb + n)*64 + i], nvp[0], nvp[1], nvp[2]};
    }
    __syncthreads();

    // this wave's 4 nodes (block-local, specie-sorted)
    int ln[4];
    #pragma unroll
    for (int j = 0; j < 4; ++j)
        ln[j] = bord[wq*4 + j];          // uniform LDS read -> broadcast

    float s0[4] = {}, s1[4] = {}, v0[4] = {}, v1[4] = {}, v2[4] = {};

    // down-projection: weights shared across the wave's 4 nodes
    for (int i = 0; i < 128; ++i) {
        const float wd0 = Wds[i*128 + lane];
        const float wd1 = Wds[i*128 + 64 + lane];
        const float wdv = Wdv[i*64 + lane];
        #pragma unroll
        for (int j = 0; j < 4; ++j) {
            const v4f a = act[ln[j]*128 + i];   // uniform ds_read_b128 bcast
            s0[j] = fmaf(a.x, wd0, s0[j]);
            s1[j] = fmaf(a.x, wd1, s1[j]);
            v0[j] = fmaf(a.y, wdv, v0[j]);
            v1[j] = fmaf(a.z, wdv, v1[j]);
            v2[j] = fmaf(a.w, wdv, v2[j]);
        }
    }

    // specie skip: 4 node streams, now mostly same-specie -> L1-shared
    const float* Ws_j[4]; const float* Wv_j[4];
    #pragma unroll
    for (int j = 0; j < 4; ++j) {
        const int spec = __builtin_amdgcn_readfirstlane(spec_idx[nb + ln[j]]);
        Ws_j[j] = Wsks + spec*8192;   // (64,128)
        Wv_j[j] = Wskv + spec*4096;   // (64,64)
    }
    for (int i = 0; i < 64; ++i) {
        #pragma unroll
        for (int j = 0; j < 4; ++j) {
            const v4f a = skp[ln[j]*64 + i];    // uniform ds_read_b128 bcast
            s0[j] = fmaf(a.x, Ws_j[j][i*128 + lane], s0[j]);
            s1[j] = fmaf(a.x, Ws_j[j][i*128 + 64 + lane], s1[j]);
            const float wv = Wv_j[j][i*64 + lane];
            v0[j] = fmaf(a.y, wv, v0[j]);
            v1[j] = fmaf(a.z, wv, v1[j]);
            v2[j] = fmaf(a.w, wv, v2[j]);
        }
    }

    #pragma unroll
    for (int j = 0; j < 4; ++j) {
        const int n = nb + ln[j];
        const float scal = swish_f(s0[j]);
        const float gate = swish_f(s1[j]);
        out[n*256 + lane]            = scal;
        out[n*256 + 64 + lane*3 + 0] = v0[j] * gate;
        out[n*256 + 64 + lane*3 + 1] = v1[j] * gate;
        out[n*256 + 64 + lane*3 + 2] = v2[j] * gate;
    }
}

// ---------------------------------------------------------------------------
extern "C" void kernel_launch(void* const* d_in, const int* in_sizes, int n_in,
                              void* d_out, int out_size, void* d_ws, size_t ws_size,
                              hipStream_t stream)
{
    (void)in_sizes; (void)n_in; (void)out_size; (void)ws_size;

    const float* vectors      = (const float*)d_in[0];
    const float* node_scalars = (const float*)d_in[1];
    const float* node_vectors = (const float*)d_in[2];
    const int*   node_specie  = (const int*)d_in[3];
    const int*   senders      = (const int*)d_in[4];
    const int*   receivers    = (const int*)d_in[5];
    const float* W_skip_s     = (const float*)d_in[6];
    const float* W_skip_v     = (const float*)d_in[7];
    const float* W_up_s       = (const float*)d_in[8];
    const float* W_up_v       = (const float*)d_in[9];
    const float* W_mlp0       = (const float*)d_in[10];
    const float* W_mlp1       = (const float*)d_in[11];
    const float* W_mlp2       = (const float*)d_in[12];
    const float* W_down_s     = (const float*)d_in[13];
    const float* W_down_v     = (const float*)d_in[14];
    float* out = (float*)d_out;

    // workspace layout: 15,360,000 f32 + perm 320k ints.
    float* ws    = (float*)d_ws;
    float* s_up  = ws;                        // N*64   = 1,280,000 f32 (quad-T)
    float* v_up  = s_up + 1280000;            // N*192  = 3,840,000    (quad-T)
    float* agg_s = v_up + 3840000;            // N*128  = 2,560,000
    float* agg_v = agg_s + 2560000;           // N*384  = 7,680,000
    int*   perm  = (int*)(agg_v + 7680000);   // E ints = 320,000
    int*   cnt    = (int*)agg_s;              // aliased scratch (dead before node_up)
    int*   cursor = cnt + 20000;

    // edge counting sort by receiver (kernels only; no runtime memops)
    hipLaunchKernelGGL(k_zero_cnt, dim3(79),   dim3(256),  0, stream, cnt);
    hipLaunchKernelGGL(k_hist,     dim3(1250), dim3(256),  0, stream, receivers, cnt);
    hipLaunchKernelGGL(k_scan,     dim3(1),    dim3(1024), 0, stream, cnt, cursor);
    hipLaunchKernelGGL(k_scatter,  dim3(1250), dim3(256),  0, stream, receivers, cursor, perm);

    hipLaunchKernelGGL(k_node_up, dim3(1250), dim3(256), 0, stream,
        node_scalars, node_vectors, W_up_s, W_up_v, s_up, v_up, agg_s, agg_v);
    hipLaunchKernelGGL(k_edge, dim3(5000), dim3(256), 0, stream,
        vectors, senders, receivers, perm, W_mlp0, W_mlp1, W_mlp2,
        s_up, v_up, agg_s, agg_v);
    hipLaunchKernelGGL(k_node_down, dim3(1250), dim3(256), 0, stream,
        node_scalars, node_vectors, node_specie, W_down_s, W_down_v,
        W_skip_s, W_skip_v, agg_s, agg_v, out);
}